// Round 2
// baseline (1144.633 us; speedup 1.0000x reference)
//
#include <hip/hip_runtime.h>

#define NN 114688      // nodes
#define NE 917504      // edges
#define NBATCH 8192    // graphs
#define GSZ 14         // nodes per graph
#define NCLS 10
#define EPSB 1e-5f
#define NSCAN 112      // NN / 1024

typedef unsigned short u16;
typedef short bf16x8 __attribute__((ext_vector_type(8)));
typedef float f32x4 __attribute__((ext_vector_type(4)));
typedef _Float16 h8t __attribute__((ext_vector_type(8)));
typedef unsigned short u16x8 __attribute__((ext_vector_type(8)));

__device__ __forceinline__ float bf2f(u16 u) {
    union { unsigned int i; float f; } v; v.i = ((unsigned int)u) << 16; return v.f;
}
__device__ __forceinline__ u16 f2bf(float f) {
    union { float f; unsigned int i; } v; v.f = f;
    unsigned int i = v.i;
    unsigned int r = i + 0x7FFFu + ((i >> 16) & 1u);   // RNE
    return (u16)(r >> 16);
}
__device__ __forceinline__ void splitbf(float y, u16& h, u16& l) {
    h = f2bf(y);
    l = f2bf(y - bf2f(h));
}

// ---------------- graph preprocessing ----------------
__global__ __launch_bounds__(256) void k_hist(const int* __restrict__ ei, int* __restrict__ counts) {
    int e = blockIdx.x * 256 + threadIdx.x;
    atomicAdd(&counts[ei[NE + e]], 1);
}

__global__ __launch_bounds__(256) void k_scan1(const int* __restrict__ counts, int* __restrict__ bsum) {
    __shared__ int red[256];
    int tid = threadIdx.x;
    int base = blockIdx.x * 1024 + tid * 4;
    int s = counts[base] + counts[base + 1] + counts[base + 2] + counts[base + 3];
    red[tid] = s; __syncthreads();
    for (int o = 128; o > 0; o >>= 1) {
        if (tid < o) red[tid] += red[tid + o];
        __syncthreads();
    }
    if (tid == 0) bsum[blockIdx.x] = red[0];
}

__global__ void k_scan2(int* bsum, int* offs) {
    if (threadIdx.x == 0) {
        int run = 0;
        for (int i = 0; i < NSCAN; i++) { int t = bsum[i]; bsum[i] = run; run += t; }
        offs[NN] = run;
    }
}

__global__ __launch_bounds__(256) void k_scan3(const int* __restrict__ counts, const int* __restrict__ bsum,
                                               int* __restrict__ offs) {
    __shared__ int ss[256];
    int tid = threadIdx.x;
    int base = blockIdx.x * 1024 + tid * 4;
    int v0 = counts[base], v1 = counts[base + 1], v2 = counts[base + 2], v3 = counts[base + 3];
    int ts = v0 + v1 + v2 + v3;
    ss[tid] = ts; __syncthreads();
    for (int o = 1; o < 256; o <<= 1) {
        int add = (tid >= o) ? ss[tid - o] : 0;
        __syncthreads();
        ss[tid] += add;
        __syncthreads();
    }
    int excl = ss[tid] - ts + bsum[blockIdx.x];
    offs[base] = excl;
    offs[base + 1] = excl + v0;
    offs[base + 2] = excl + v0 + v1;
    offs[base + 3] = excl + v0 + v1 + v2;
}

__global__ __launch_bounds__(256) void k_dis_cursor(const int* __restrict__ counts, const int* __restrict__ offs,
                                                    float* __restrict__ dis, int* __restrict__ cursor) {
    int n = blockIdx.x * 256 + threadIdx.x;
    dis[n] = rsqrtf((float)counts[n] + 1.0f);
    cursor[n] = offs[n];
}

// scatter edges into CSR; also accumulate wsa[d] = sum_e dis[src] (for the agg-commute fold)
__global__ __launch_bounds__(256) void k_scatter(const int* __restrict__ ei, int* __restrict__ cursor,
                                                 int* __restrict__ srcs, float* __restrict__ sd,
                                                 const float* __restrict__ dis, float* __restrict__ wsa) {
    int e = blockIdx.x * 256 + threadIdx.x;
    int d = ei[NE + e], s = ei[e];
    int p = atomicAdd(&cursor[d], 1);
    float w = dis[s];
    srcs[p] = s;
    sd[p] = w;
    atomicAdd(&wsa[d], w);
}

// transpose + split fp32 W[K,F] -> bf16 Wh/Wl [F,K] (no affine; layer 1)
__global__ __launch_bounds__(256) void k_tsplit(const float* __restrict__ Wsrc,
                                                u16* __restrict__ Wh, u16* __restrict__ Wl,
                                                int K, int F) {
    int i = blockIdx.x * 256 + threadIdx.x;
    if (i < K * F) {
        int k = i / F, f = i % F;
        u16 h, l; splitbf(Wsrc[i], h, l);
        Wh[f * K + k] = h;
        Wl[f * K + k] = l;
    }
}

// PARALLEL BN-fold, part 1: Wh/Wl[f,k] = split(sc[k]*W[k,f]) — one thread per element
__global__ __launch_bounds__(256) void k_wsplit(const float* __restrict__ W, const float* __restrict__ sc,
                                                u16* __restrict__ Wh, u16* __restrict__ Wl,
                                                int K, int F) {
    int i = blockIdx.x * 256 + threadIdx.x;
    if (i < K * F) {
        int k = i / F, f = i % F;
        u16 h, l; splitbf(sc[k] * W[i], h, l);
        Wh[f * K + k] = h;
        Wl[f * K + k] = l;
    }
}

// PARALLEL BN-fold, part 2: c2[f] = sum_k sh[k]*W[k,f] — one wave per column
__global__ __launch_bounds__(256) void k_wc2(const float* __restrict__ W, const float* __restrict__ sh,
                                             float* __restrict__ c2, int K, int F) {
    int wv = (blockIdx.x * 256 + threadIdx.x) >> 6;
    int lane = threadIdx.x & 63;
    if (wv >= F) return;
    float acc = 0.f;
    for (int k = lane; k < K; k += 64) acc += sh[k] * W[k * F + wv];
#pragma unroll
    for (int o = 1; o < 64; o <<= 1) acc += __shfl_xor(acc, o);
    if (lane == 0) c2[wv] = acc;
}

// ---------------- split MFMA GEMM: C = A @ W' (+epilogues), fp32-grade via bf16x3 ----------------
// AFP32: A is fp32 (layer 1, split at stage). Else A is two exact bf16 planes Ahi/Alo [N][K].
// W pre-split (+BN-folded) bf16 hi/lo [Fout][K]. C2: init acc with per-column constant. C fp16.
// TEPI (layer-2 agg-commute epilogue): v = acc + wsum[row]*c2[col] + bias[col]; t = relu(v);
//   write exact bf16 hi/lo planes Thi/Tlo and accumulate per-column BN stats into Sg/Qg.
template<int BM, int BN, int WCOLS, bool AFP32, bool C2, bool TEPI>
__global__ __launch_bounds__(256) void k_gemm(
    const float* __restrict__ Af, const u16* __restrict__ Ahi, const u16* __restrict__ Alo,
    const u16* __restrict__ Wh, const u16* __restrict__ Wl,
    _Float16* __restrict__ C, const int K, const int Fout, const float* __restrict__ c2,
    const float* __restrict__ bias, const float* __restrict__ wsa, const float* __restrict__ disv,
    u16* __restrict__ Thi, u16* __restrict__ Tlo, float* __restrict__ Sg, float* __restrict__ Qg)
{
    constexpr int AST = 40;                // 32 + 8 pad
    __shared__ u16 Ah[BM][AST], Al[BM][AST];
    __shared__ u16 Bh[BN][AST], Bl[BN][AST];
    __shared__ float redS[TEPI ? BN : 1], redQ[TEPI ? BN : 1];

    const int tid = threadIdx.x;
    const int row0 = blockIdx.y * BM;
    const int col0 = blockIdx.x * BN;

    const int wave = tid >> 6, lane = tid & 63;
    const int mb = (wave / WCOLS) * 64;
    const int nb = (wave % WCOLS) * 64;
    const int lm = lane & 15;
    const int lk = (lane >> 4) * 8;
    const int cb = col0 + nb + lm;

    if constexpr (TEPI) {
        for (int i = tid; i < BN; i += 256) { redS[i] = 0.f; redQ[i] = 0.f; }
    }

    float c2v[4] = {0.f, 0.f, 0.f, 0.f};
    if constexpr (C2) {
#pragma unroll
        for (int ni = 0; ni < 4; ni++) c2v[ni] = c2[cb + ni * 16];
    }

    f32x4 acc[4][4];
#pragma unroll
    for (int i = 0; i < 4; i++)
#pragma unroll
        for (int j = 0; j < 4; j++)
#pragma unroll
            for (int r = 0; r < 4; r++) acc[i][j][r] = c2v[j];

    const int stg_r = tid >> 3;        // 0..31
    const int stg_c = (tid & 7) * 4;   // 0,4..28

    for (int k0 = 0; k0 < K; k0 += 32) {
        __syncthreads();
#pragma unroll
        for (int p = 0; p < BM / 32; p++) {
            const int r = p * 32 + stg_r;
            if constexpr (AFP32) {
                const float4 v = *(const float4*)(Af + (size_t)(row0 + r) * K + k0 + stg_c);
                float y[4] = {v.x, v.y, v.z, v.w};
                ushort4 hv, lv;
#pragma unroll
                for (int q = 0; q < 4; q++) splitbf(y[q], ((u16*)&hv)[q], ((u16*)&lv)[q]);
                *(ushort4*)&Ah[r][stg_c] = hv;
                *(ushort4*)&Al[r][stg_c] = lv;
            } else {
                *(ushort4*)&Ah[r][stg_c] = *(const ushort4*)(Ahi + (size_t)(row0 + r) * K + k0 + stg_c);
                *(ushort4*)&Al[r][stg_c] = *(const ushort4*)(Alo + (size_t)(row0 + r) * K + k0 + stg_c);
            }
        }
#pragma unroll
        for (int p = 0; p < BN / 32; p++) {
            const int n = p * 32 + stg_r;
            *(ushort4*)&Bh[n][stg_c] = *(const ushort4*)(Wh + (size_t)(col0 + n) * K + k0 + stg_c);
            *(ushort4*)&Bl[n][stg_c] = *(const ushort4*)(Wl + (size_t)(col0 + n) * K + k0 + stg_c);
        }
        __syncthreads();

        bf16x8 ah[4], al[4], bh[4], bl[4];
#pragma unroll
        for (int mi = 0; mi < 4; mi++) {
            ah[mi] = *(const bf16x8*)&Ah[mb + mi * 16 + lm][lk];
            al[mi] = *(const bf16x8*)&Al[mb + mi * 16 + lm][lk];
        }
#pragma unroll
        for (int ni = 0; ni < 4; ni++) {
            bh[ni] = *(const bf16x8*)&Bh[nb + ni * 16 + lm][lk];
            bl[ni] = *(const bf16x8*)&Bl[nb + ni * 16 + lm][lk];
        }
#pragma unroll
        for (int mi = 0; mi < 4; mi++)
#pragma unroll
            for (int ni = 0; ni < 4; ni++) {
                acc[mi][ni] = __builtin_amdgcn_mfma_f32_16x16x32_bf16(al[mi], bh[ni], acc[mi][ni], 0, 0, 0);
                acc[mi][ni] = __builtin_amdgcn_mfma_f32_16x16x32_bf16(ah[mi], bl[ni], acc[mi][ni], 0, 0, 0);
                acc[mi][ni] = __builtin_amdgcn_mfma_f32_16x16x32_bf16(ah[mi], bh[ni], acc[mi][ni], 0, 0, 0);
            }
    }

    const int rb = row0 + mb + (lane >> 4) * 4;
    if constexpr (TEPI) {
        float c2l[4], bl4[4];
#pragma unroll
        for (int ni = 0; ni < 4; ni++) { c2l[ni] = c2[cb + ni * 16]; bl4[ni] = bias[cb + ni * 16]; }
        float ws[4][4];
#pragma unroll
        for (int mi = 0; mi < 4; mi++)
#pragma unroll
            for (int r = 0; r < 4; r++) {
                const int row = rb + mi * 16 + r;
                const float d = disv[row];
                ws[mi][r] = d * wsa[row] + d * d;
            }
#pragma unroll
        for (int ni = 0; ni < 4; ni++) {
            float s = 0.f, q = 0.f;
#pragma unroll
            for (int mi = 0; mi < 4; mi++)
#pragma unroll
                for (int r = 0; r < 4; r++) {
                    float v = acc[mi][ni][r] + ws[mi][r] * c2l[ni] + bl4[ni];
                    v = fmaxf(v, 0.f);
                    s += v; q += v * v;
                    u16 hh, ll; splitbf(v, hh, ll);
                    const size_t idx = (size_t)(rb + mi * 16 + r) * Fout + cb + ni * 16;
                    Thi[idx] = hh;
                    Tlo[idx] = ll;
                }
            atomicAdd(&redS[nb + ni * 16 + lm], s);
            atomicAdd(&redQ[nb + ni * 16 + lm], q);
        }
        __syncthreads();
        for (int i = tid; i < BN; i += 256) {
            atomicAdd(&Sg[col0 + i], redS[i]);
            atomicAdd(&Qg[col0 + i], redQ[i]);
        }
    } else {
#pragma unroll
        for (int mi = 0; mi < 4; mi++)
#pragma unroll
            for (int ni = 0; ni < 4; ni++)
#pragma unroll
                for (int r = 0; r < 4; r++)
                    C[(size_t)(rb + mi * 16 + r) * Fout + cb + ni * 16] = (_Float16)acc[mi][ni][r];
    }
}

// ---------------- aggregation: t = relu(dn*sum(sd_e*h_s) + dn^2*h_n + b), fused BN stats --------
// h fp16 [N][CH]. FP16OUT: write t as fp16 single plane (next consumer is a linear agg).
// Else: write t as exact bf16 hi/lo planes [N][CH] (next consumer is a GEMM/smm A-operand).
template<int CH, bool FP16OUT>
__global__ __launch_bounds__(256) void k_agg(
    const _Float16* __restrict__ h, u16* __restrict__ thi, u16* __restrict__ tlo,
    const float* __restrict__ bias,
    const int* __restrict__ off, const int* __restrict__ srcs, const float* __restrict__ sd,
    const float* __restrict__ dis, float* __restrict__ statS, float* __restrict__ statQ,
    _Float16* __restrict__ tf)
{
    constexpr int ECH = 16;            // channels per lane (32B fp16)
    constexpr int LPG = CH / ECH;      // lanes per edge-group
    constexpr int NSUB = 64 / LPG;     // edges in flight per wave
    __shared__ float redS[CH], redQ[CH];
    const int tid = threadIdx.x;
    for (int i = tid; i < CH; i += 256) { redS[i] = 0.f; redQ[i] = 0.f; }
    __syncthreads();

    const int lane = tid & 63;
    const int sub = lane / LPG;
    const int c = (lane % LPG) * ECH;
    const int wid = (blockIdx.x * 256 + tid) >> 6;
    const int nw = (gridDim.x * 256) >> 6;

    float bs[ECH], bq[ECH], bv[ECH];
#pragma unroll
    for (int v = 0; v < ECH; v++) { bs[v] = 0.f; bq[v] = 0.f; bv[v] = bias[c + v]; }

    for (int n = wid; n < NN; n += nw) {
        const int p0 = off[n], p1 = off[n + 1];
        float a[ECH];
#pragma unroll
        for (int v = 0; v < ECH; v++) a[v] = 0.f;

        int p = p0 + sub;
        int s = 0; float w = 0.f;
        if (p < p1) { s = srcs[p]; w = sd[p]; }
        while (p < p1) {
            const int pn = p + NSUB;
            int s2 = 0; float w2 = 0.f;
            if (pn < p1) { s2 = srcs[pn]; w2 = sd[pn]; }   // prefetch next edge
            const _Float16* hr = h + (size_t)s * CH + c;
            h8t hv0 = *(const h8t*)hr;
            h8t hv1 = *(const h8t*)(hr + 8);
#pragma unroll
            for (int v = 0; v < 8; v++) { a[v] += w * (float)hv0[v]; a[v + 8] += w * (float)hv1[v]; }
            s = s2; w = w2; p = pn;
        }
        // merge edge-group partials across sub-wavelets
#pragma unroll
        for (int o = LPG; o < 64; o <<= 1) {
#pragma unroll
            for (int v = 0; v < ECH; v++) a[v] += __shfl_xor(a[v], o);
        }
        if (sub == 0) {
            const float dn = dis[n];
            const float dn2 = dn * dn;
            const _Float16* hr = h + (size_t)n * CH + c;
            h8t hn0 = *(const h8t*)hr;
            h8t hn1 = *(const h8t*)(hr + 8);
            float o16[ECH];
#pragma unroll
            for (int v = 0; v < 8; v++) {
                o16[v] = fmaxf(dn * a[v] + dn2 * (float)hn0[v] + bv[v], 0.f);
                o16[v + 8] = fmaxf(dn * a[v + 8] + dn2 * (float)hn1[v] + bv[v + 8], 0.f);
            }
#pragma unroll
            for (int v = 0; v < ECH; v++) { bs[v] += o16[v]; bq[v] += o16[v] * o16[v]; }
            if constexpr (FP16OUT) {
                h8t o0, o1;
#pragma unroll
                for (int v = 0; v < 8; v++) { o0[v] = (_Float16)o16[v]; o1[v] = (_Float16)o16[v + 8]; }
                _Float16* tr = tf + (size_t)n * CH + c;
                *(h8t*)tr = o0; *(h8t*)(tr + 8) = o1;
            } else {
                u16x8 hv0, lv0, hv1, lv1;
#pragma unroll
                for (int v = 0; v < 8; v++) {
                    splitbf(o16[v], ((u16*)&hv0)[v], ((u16*)&lv0)[v]);
                    splitbf(o16[v + 8], ((u16*)&hv1)[v], ((u16*)&lv1)[v]);
                }
                u16* th = thi + (size_t)n * CH + c;
                u16* tl = tlo + (size_t)n * CH + c;
                *(u16x8*)th = hv0; *(u16x8*)(th + 8) = hv1;
                *(u16x8*)tl = lv0; *(u16x8*)(tl + 8) = lv1;
            }
        }
    }
    if (sub == 0) {
#pragma unroll
        for (int v = 0; v < ECH; v++) { atomicAdd(&redS[c + v], bs[v]); atomicAdd(&redQ[c + v], bq[v]); }
    }
    __syncthreads();
    for (int i = tid; i < CH; i += 256) { atomicAdd(&statS[i], redS[i]); atomicAdd(&statQ[i], redQ[i]); }
}

// ---------------- pure linear aggregation: u = dn*sum(sd_e*t_s) + dn^2*t_n ----------------
// t fp16 [N][CH]; u written as exact bf16 hi/lo planes (GEMM A-operand). No bias/relu/stats.
template<int CH>
__global__ __launch_bounds__(256) void k_agglin(
    const _Float16* __restrict__ t, u16* __restrict__ uhi, u16* __restrict__ ulo,
    const int* __restrict__ off, const int* __restrict__ srcs, const float* __restrict__ sd,
    const float* __restrict__ dis)
{
    constexpr int ECH = 16;
    constexpr int LPG = CH / ECH;
    constexpr int NSUB = 64 / LPG;
    const int tid = threadIdx.x;
    const int lane = tid & 63;
    const int sub = lane / LPG;
    const int c = (lane % LPG) * ECH;
    const int wid = (blockIdx.x * 256 + tid) >> 6;
    const int nw = (gridDim.x * 256) >> 6;

    for (int n = wid; n < NN; n += nw) {
        const int p0 = off[n], p1 = off[n + 1];
        float a[ECH];
#pragma unroll
        for (int v = 0; v < ECH; v++) a[v] = 0.f;

        int p = p0 + sub;
        int s = 0; float w = 0.f;
        if (p < p1) { s = srcs[p]; w = sd[p]; }
        while (p < p1) {
            const int pn = p + NSUB;
            int s2 = 0; float w2 = 0.f;
            if (pn < p1) { s2 = srcs[pn]; w2 = sd[pn]; }
            const _Float16* hr = t + (size_t)s * CH + c;
            h8t hv0 = *(const h8t*)hr;
            h8t hv1 = *(const h8t*)(hr + 8);
#pragma unroll
            for (int v = 0; v < 8; v++) { a[v] += w * (float)hv0[v]; a[v + 8] += w * (float)hv1[v]; }
            s = s2; w = w2; p = pn;
        }
#pragma unroll
        for (int o = LPG; o < 64; o <<= 1) {
#pragma unroll
            for (int v = 0; v < ECH; v++) a[v] += __shfl_xor(a[v], o);
        }
        if (sub == 0) {
            const float dn = dis[n];
            const float dn2 = dn * dn;
            const _Float16* hr = t + (size_t)n * CH + c;
            h8t hn0 = *(const h8t*)hr;
            h8t hn1 = *(const h8t*)(hr + 8);
            u16x8 hv0, lv0, hv1, lv1;
#pragma unroll
            for (int v = 0; v < 8; v++) {
                float o0 = dn * a[v] + dn2 * (float)hn0[v];
                float o1 = dn * a[v + 8] + dn2 * (float)hn1[v];
                splitbf(o0, ((u16*)&hv0)[v], ((u16*)&lv0)[v]);
                splitbf(o1, ((u16*)&hv1)[v], ((u16*)&lv1)[v]);
            }
            u16* th = uhi + (size_t)n * CH + c;
            u16* tl = ulo + (size_t)n * CH + c;
            *(u16x8*)th = hv0; *(u16x8*)(th + 8) = hv1;
            *(u16x8*)tl = lv0; *(u16x8*)(tl + 8) = lv1;
        }
    }
}

// ---------------- BN stats -> scale/shift ----------------
__global__ void k_bnpar(const float* __restrict__ S, const float* __restrict__ Q,
                        const float* __restrict__ g, const float* __restrict__ b,
                        float* __restrict__ sc, float* __restrict__ sh, int F) {
    int c = threadIdx.x;
    if (c >= F) return;
    const float invn = 1.0f / (float)NN;
    float mean = S[c] * invn;
    float var = Q[c] * invn - mean * mean;
    float s = g[c] * rsqrtf(fmaxf(var, 0.f) + EPSB);
    sc[c] = s;
    sh[c] = b[c] - mean * s;
}

// ---------------- small dense layer: C[N,F] = affine(A)[N,K] @ W[K,F] (+bias) ----------------
// A = bf16 hi/lo planes, C fp16, fp32 compute. STATS: fused per-column sum/sumsq of acc.
template<int K, int F, bool BIAS, bool STATS>
__global__ __launch_bounds__(256) void k_smm(
    const u16* __restrict__ Ahi, const u16* __restrict__ Alo,
    const float* __restrict__ Wf, const float* __restrict__ bias,
    _Float16* __restrict__ C, const float* __restrict__ sc, const float* __restrict__ sh,
    float* __restrict__ Sg, float* __restrict__ Qg)
{
    __shared__ float Wl[K * F];
    __shared__ float scl[K], shl[K], bl[F];
    __shared__ float redS[F], redQ[F];
    const int tid = threadIdx.x;
    for (int i = tid; i < K * F; i += 256) Wl[i] = Wf[i];
    if (tid < K) { scl[tid] = sc[tid]; shl[tid] = sh[tid]; }
    if (tid < F) {
        bl[tid] = 0.f;
        if constexpr (BIAS) bl[tid] = bias[tid];
        if constexpr (STATS) { redS[tid] = 0.f; redQ[tid] = 0.f; }
    }
    __syncthreads();
    const int n = blockIdx.x * 256 + tid;
    float acc[F];
#pragma unroll
    for (int f = 0; f < F; f++) acc[f] = bl[f];
    const u16* ah = Ahi + (size_t)n * K;
    const u16* al = Alo + (size_t)n * K;
    for (int k = 0; k < K; k += 4) {
        ushort4 hv = *(const ushort4*)(ah + k);
        ushort4 lv = *(const ushort4*)(al + k);
        float y0 = (bf2f(hv.x) + bf2f(lv.x)) * scl[k] + shl[k];
        float y1 = (bf2f(hv.y) + bf2f(lv.y)) * scl[k + 1] + shl[k + 1];
        float y2 = (bf2f(hv.z) + bf2f(lv.z)) * scl[k + 2] + shl[k + 2];
        float y3 = (bf2f(hv.w) + bf2f(lv.w)) * scl[k + 3] + shl[k + 3];
#pragma unroll
        for (int f = 0; f < F; f += 4) {
            float4 w0 = *(const float4*)&Wl[k * F + f];
            float4 w1 = *(const float4*)&Wl[(k + 1) * F + f];
            float4 w2 = *(const float4*)&Wl[(k + 2) * F + f];
            float4 w3 = *(const float4*)&Wl[(k + 3) * F + f];
            acc[f + 0] += y0 * w0.x + y1 * w1.x + y2 * w2.x + y3 * w3.x;
            acc[f + 1] += y0 * w0.y + y1 * w1.y + y2 * w2.y + y3 * w3.y;
            acc[f + 2] += y0 * w0.z + y1 * w1.z + y2 * w2.z + y3 * w3.z;
            acc[f + 3] += y0 * w0.w + y1 * w1.w + y2 * w2.w + y3 * w3.w;
        }
    }
    _Float16* cr = C + (size_t)n * F;
#pragma unroll
    for (int f = 0; f < F; f++) cr[f] = (_Float16)acc[f];
    if constexpr (STATS) {
        float s[F], q[F];
#pragma unroll
        for (int f = 0; f < F; f++) { s[f] = acc[f]; q[f] = acc[f] * acc[f]; }
#pragma unroll
        for (int o = 1; o < 64; o <<= 1) {
#pragma unroll
            for (int f = 0; f < F; f++) { s[f] += __shfl_xor(s[f], o); q[f] += __shfl_xor(q[f], o); }
        }
        if ((tid & 63) == 0) {
#pragma unroll
            for (int f = 0; f < F; f++) { atomicAdd(&redS[f], s[f]); atomicAdd(&redQ[f], q[f]); }
        }
        __syncthreads();
        for (int i = tid; i < F; i += 256) { atomicAdd(&Sg[i], redS[i]); atomicAdd(&Qg[i], redQ[i]); }
    }
}

// ---------------- gate layer 2: g2 = relu(bn1(g1)) @ gW2 + gb2, fused scalar stats ----------------
__global__ __launch_bounds__(256) void k_gate2(const _Float16* __restrict__ g1,
                                               const float* __restrict__ sc, const float* __restrict__ sh,
                                               const float* __restrict__ w2, const float* __restrict__ b2,
                                               float* __restrict__ g2,
                                               float* __restrict__ Sg, float* __restrict__ Qg) {
    __shared__ float wl[16], scl[16], shl[16], b2l[1];
    __shared__ float redSg[1], redQg[1];
    const int tid = threadIdx.x;
    if (tid < 16) { wl[tid] = w2[tid]; scl[tid] = sc[tid]; shl[tid] = sh[tid]; }
    if (tid == 0) { b2l[0] = b2[0]; redSg[0] = 0.f; redQg[0] = 0.f; }
    __syncthreads();
    const int n = blockIdx.x * 256 + tid;
    const _Float16* r = g1 + (size_t)n * 16;
    float acc = b2l[0];
#pragma unroll
    for (int k = 0; k < 16; k++) {
        float y = fmaxf((float)r[k] * scl[k] + shl[k], 0.f);
        acc += y * wl[k];
    }
    g2[n] = acc;
    float s = acc, q = acc * acc;
#pragma unroll
    for (int o = 1; o < 64; o <<= 1) { s += __shfl_xor(s, o); q += __shfl_xor(q, o); }
    if ((tid & 63) == 0) { atomicAdd(&redSg[0], s); atomicAdd(&redQg[0], q); }
    __syncthreads();
    if (tid == 0) { atomicAdd(&Sg[0], redSg[0]); atomicAdd(&Qg[0], redQg[0]); }
}

// ---------------- segment softmax + pooling + FC + softmax ----------------
__global__ __launch_bounds__(256) void k_pool(const u16* __restrict__ t4hi, const u16* __restrict__ t4lo,
                                              const float* __restrict__ sc4, const float* __restrict__ sh4,
                                              const float* __restrict__ g2,
                                              const float* __restrict__ gsc2, const float* __restrict__ gsh2,
                                              const float* __restrict__ fcW, const float* __restrict__ fcb,
                                              float* __restrict__ out) {
    __shared__ float fw[32 * NCLS], fbl[NCLS], sc4l[32], sh4l[32];
    const int tid = threadIdx.x;
    for (int i = tid; i < 32 * NCLS; i += 256) fw[i] = fcW[i];
    if (tid < NCLS) fbl[tid] = fcb[tid];
    if (tid < 32) { sc4l[tid] = sc4[tid]; sh4l[tid] = sh4[tid]; }
    __syncthreads();
    const int b = blockIdx.x * 256 + tid;
    const float s2 = gsc2[0], h2 = gsh2[0];
    const int base = b * GSZ;

    float gv[GSZ];
    float m = -1e30f;
#pragma unroll
    for (int i = 0; i < GSZ; i++) {
        float v = fmaxf(g2[base + i] * s2 + h2, 0.f);
        gv[i] = v; m = fmaxf(m, v);
    }
    float ssum = 0.f;
#pragma unroll
    for (int i = 0; i < GSZ; i++) { float e = __expf(gv[i] - m); gv[i] = e; ssum += e; }
    const float inv = 1.0f / ssum;

    float pooled[32];
#pragma unroll
    for (int c = 0; c < 32; c++) pooled[c] = 0.f;
#pragma unroll
    for (int i = 0; i < GSZ; i++) {
        const float a = gv[i] * inv;
        const u16* th = t4hi + (size_t)(base + i) * 32;
        const u16* tl = t4lo + (size_t)(base + i) * 32;
#pragma unroll
        for (int c = 0; c < 32; c += 4) {
            ushort4 hv = *(const ushort4*)(th + c);
            ushort4 lv = *(const ushort4*)(tl + c);
            pooled[c + 0] += a * ((bf2f(hv.x) + bf2f(lv.x)) * sc4l[c + 0] + sh4l[c + 0]);
            pooled[c + 1] += a * ((bf2f(hv.y) + bf2f(lv.y)) * sc4l[c + 1] + sh4l[c + 1]);
            pooled[c + 2] += a * ((bf2f(hv.z) + bf2f(lv.z)) * sc4l[c + 2] + sh4l[c + 2]);
            pooled[c + 3] += a * ((bf2f(hv.w) + bf2f(lv.w)) * sc4l[c + 3] + sh4l[c + 3]);
        }
    }
    float lg[NCLS];
    float mx = -1e30f;
#pragma unroll
    for (int j = 0; j < NCLS; j++) {
        float a = fbl[j];
#pragma unroll
        for (int c = 0; c < 32; c++) a += pooled[c] * fw[c * NCLS + j];
        lg[j] = a; mx = fmaxf(mx, a);
    }
    float es = 0.f;
#pragma unroll
    for (int j = 0; j < NCLS; j++) { float e = __expf(lg[j] - mx); lg[j] = e; es += e; }
    const float iv = 1.0f / es;
#pragma unroll
    for (int j = 0; j < NCLS; j++) out[b * NCLS + j] = lg[j] * iv;
}

// ---------------- host ----------------
extern "C" void kernel_launch(void* const* d_in, const int* in_sizes, int n_in,
                              void* d_out, int out_size, void* d_ws, size_t ws_size,
                              hipStream_t stream) {
    (void)in_sizes; (void)n_in; (void)out_size; (void)ws_size;
    const float* x    = (const float*)d_in[0];
    const int*   ei   = (const int*)d_in[1];
    const float* W1   = (const float*)d_in[2];
    const float* b1   = (const float*)d_in[3];
    const float* bn1g = (const float*)d_in[4];
    const float* bn1b = (const float*)d_in[5];
    const float* W2   = (const float*)d_in[6];
    const float* b2   = (const float*)d_in[7];
    const float* bn2g = (const float*)d_in[8];
    const float* bn2b = (const float*)d_in[9];
    const float* W3   = (const float*)d_in[10];
    const float* b3   = (const float*)d_in[11];
    const float* bn3g = (const float*)d_in[12];
    const float* bn3b = (const float*)d_in[13];
    const float* W4   = (const float*)d_in[14];
    const float* b4   = (const float*)d_in[15];
    const float* bn4g = (const float*)d_in[16];
    const float* bn4b = (const float*)d_in[17];
    const float* gW1  = (const float*)d_in[18];
    const float* gb1  = (const float*)d_in[19];
    const float* gbn1g = (const float*)d_in[20];
    const float* gbn1b = (const float*)d_in[21];
    const float* gW2  = (const float*)d_in[22];
    const float* gb2  = (const float*)d_in[23];
    const float* gbn2g = (const float*)d_in[24];
    const float* gbn2b = (const float*)d_in[25];
    const float* fcW  = (const float*)d_in[26];
    const float* fcb  = (const float*)d_in[27];
    float* out = (float*)d_out;

    char* base = (char*)d_ws;
    size_t off_ = 0;
    auto carve = [&](size_t bytes) -> char* {
        char* p = base + off_;
        off_ = (off_ + bytes + 255) & ~(size_t)255;
        return p;
    };
    int*   counts = (int*)carve((size_t)NN * 4);
    float* stats  = (float*)carve(994 * 4);
    float* wsa    = (float*)carve((size_t)NN * 4);
    const size_t zero_bytes = off_;
    int*   offs   = (int*)carve((size_t)(NN + 1) * 4);
    int*   cursor = (int*)carve((size_t)NN * 4);
    int*   srcs   = (int*)carve((size_t)NE * 4);
    float* sd     = (float*)carve((size_t)NE * 4);
    float* dis    = (float*)carve((size_t)NN * 4);
    int*   bsum   = (int*)carve(NSCAN * 4);
    float* pars   = (float*)carve(994 * 4);
    u16*   Wt1h   = (u16*)carve(512 * 128 * 2);
    u16*   Wt1l   = (u16*)carve(512 * 128 * 2);
    u16*   Wt2h   = (u16*)carve(128 * 256 * 2);
    u16*   Wt2l   = (u16*)carve(128 * 256 * 2);
    u16*   Wt3h   = (u16*)carve(256 * 64 * 2);
    u16*   Wt3l   = (u16*)carve(256 * 64 * 2);
    float* c2_2   = (float*)carve(256 * 4);
    float* c2_3   = (float*)carve(64 * 4);
    float* g2raw  = (float*)carve((size_t)NN * 4);
    _Float16* P   = (_Float16*)carve((size_t)NN * 256 * 2);   // h buffer (fp16, up to 256 ch)
    u16*   Qhi    = (u16*)carve((size_t)NN * 128 * 2);        // t/u planes (<=128 ch)
    u16*   Qlo    = (u16*)carve((size_t)NN * 128 * 2);
    u16*   Rhi    = (u16*)carve((size_t)NN * 256 * 2);        // t2 planes (256 ch)
    u16*   Rlo    = (u16*)carve((size_t)NN * 256 * 2);
    // t1 fp16 single plane lives in the upper half of P (h1 only uses [N,128])
    _Float16* T1f = P + (size_t)NN * 128;

    float* S1 = stats;      float* Q1s = S1 + 128;
    float* S2 = Q1s + 128;  float* Q2s = S2 + 256;
    float* S3 = Q2s + 256;  float* Q3s = S3 + 64;
    float* S4 = Q3s + 64;   float* Q4s = S4 + 32;
    float* gS1 = Q4s + 32;  float* gQ1 = gS1 + 16;
    float* gS2 = gQ1 + 16;  float* gQ2 = gS2 + 1;

    float* sc1 = pars;      float* sh1 = sc1 + 128;
    float* sc2 = sh1 + 128; float* sh2 = sc2 + 256;
    float* sc3 = sh2 + 256; float* sh3 = sc3 + 64;
    float* sc4 = sh3 + 64;  float* sh4 = sc4 + 32;
    float* gsc1 = sh4 + 32; float* gsh1 = gsc1 + 16;
    float* gsc2 = gsh1 + 16; float* gsh2 = gsc2 + 1;

    hipMemsetAsync(d_ws, 0, zero_bytes, stream);

    k_hist<<<NE / 256, 256, 0, stream>>>(ei, counts);
    k_scan1<<<NSCAN, 256, 0, stream>>>(counts, bsum);
    k_scan2<<<1, 64, 0, stream>>>(bsum, offs);
    k_scan3<<<NSCAN, 256, 0, stream>>>(counts, bsum, offs);
    k_dis_cursor<<<NN / 256, 256, 0, stream>>>(counts, offs, dis, cursor);
    k_scatter<<<NE / 256, 256, 0, stream>>>(ei, cursor, srcs, sd, dis, wsa);
    k_tsplit<<<(512 * 128 + 255) / 256, 256, 0, stream>>>(W1, Wt1h, Wt1l, 512, 128);

    // layer 1: h1 = x @ W1 -> P (N x 128 fp16); t1 = relu(agg(h1)+b1) -> T1f fp16 + BN1 stats
    k_gemm<128, 128, 2, true, false, false><<<dim3(1, NN / 128), 256, 0, stream>>>(
        x, nullptr, nullptr, Wt1h, Wt1l, P, 512, 128, nullptr,
        nullptr, nullptr, nullptr, nullptr, nullptr, nullptr, nullptr);
    k_agg<128, true><<<2048, 256, 0, stream>>>(P, nullptr, nullptr, b1, offs, srcs, sd, dis, S1, Q1s, T1f);
    k_bnpar<<<1, 256, 0, stream>>>(S1, Q1s, bn1g, bn1b, sc1, sh1, 128);

    // layer 2, agg-commute: u = agg(t1) on 128 ch -> Q planes; then
    // t2 = relu(u@(sc1*W2) + wsum*(sh1@W2) + b2) in the GEMM epilogue -> R planes + BN2 stats
    k_agglin<128><<<2048, 256, 0, stream>>>(T1f, Qhi, Qlo, offs, srcs, sd, dis);
    k_wsplit<<<(128 * 256 + 255) / 256, 256, 0, stream>>>(W2, sc1, Wt2h, Wt2l, 128, 256);
    k_wc2<<<(256 * 64 + 255) / 256, 256, 0, stream>>>(W2, sh1, c2_2, 128, 256);
    k_gemm<128, 128, 2, false, false, true><<<dim3(2, NN / 128), 256, 0, stream>>>(
        nullptr, Qhi, Qlo, Wt2h, Wt2l, nullptr, 128, 256, c2_2,
        b2, wsa, dis, Rhi, Rlo, S2, Q2s);
    k_bnpar<<<1, 256, 0, stream>>>(S2, Q2s, bn2g, bn2b, sc2, sh2, 256);

    // layer 3 (BN folded into W3): h3 = t2 @ W3' + c2 -> P (N x 64); t3 -> Q planes
    k_wsplit<<<(256 * 64 + 255) / 256, 256, 0, stream>>>(W3, sc2, Wt3h, Wt3l, 256, 64);
    k_wc2<<<(64 * 64 + 255) / 256, 256, 0, stream>>>(W3, sh2, c2_3, 256, 64);
    k_gemm<256, 64, 1, false, true, false><<<dim3(1, NN / 256), 256, 0, stream>>>(
        nullptr, Rhi, Rlo, Wt3h, Wt3l, P, 256, 64, c2_3,
        nullptr, nullptr, nullptr, nullptr, nullptr, nullptr, nullptr);
    k_agg<64, false><<<2048, 256, 0, stream>>>(P, Qhi, Qlo, b3, offs, srcs, sd, dis, S3, Q3s, nullptr);
    k_bnpar<<<1, 256, 0, stream>>>(S3, Q3s, bn3g, bn3b, sc3, sh3, 64);

    // layer 4: h4 = bn(t3) @ W4 -> P (N x 32 fp16); t4 -> Q planes (32 ch)
    k_smm<64, 32, false, false><<<NN / 256, 256, 0, stream>>>(Qhi, Qlo, W4, nullptr, P, sc3, sh3,
                                                              nullptr, nullptr);
    k_agg<32, false><<<2048, 256, 0, stream>>>(P, Qhi, Qlo, b4, offs, srcs, sd, dis, S4, Q4s, nullptr);
    k_bnpar<<<1, 256, 0, stream>>>(S4, Q4s, bn4g, bn4b, sc4, sh4, 32);

    // gate 1: g1 = bn4(t4) @ gW1 + gb1 -> P (N x 16 fp16), stats fused
    k_smm<32, 16, true, true><<<NN / 256, 256, 0, stream>>>(Qhi, Qlo, gW1, gb1, P, sc4, sh4, gS1, gQ1);
    k_bnpar<<<1, 256, 0, stream>>>(gS1, gQ1, gbn1g, gbn1b, gsc1, gsh1, 16);

    // gate 2: g2 = relu(bn(g1)) @ gW2 + gb2 -> g2raw (N, fp32), stats fused
    k_gate2<<<NN / 256, 256, 0, stream>>>(P, gsc1, gsh1, gW2, gb2, g2raw, gS2, gQ2);
    k_bnpar<<<1, 256, 0, stream>>>(gS2, gQ2, gbn2g, gbn2b, gsc2, gsh2, 1);

    // pooling + FC + softmax
    k_pool<<<NBATCH / 256, 256, 0, stream>>>(Qhi, Qlo, sc4, sh4, g2raw, gsc2, gsh2, fcW, fcb, out);
}

// Round 5
// 974.875 us; speedup vs baseline: 1.1741x; 1.1741x over previous
//
#include <hip/hip_runtime.h>

#define NN 114688      // nodes
#define NE 917504      // edges
#define NBATCH 8192    // graphs
#define GSZ 14         // nodes per graph
#define NCLS 10
#define EPSB 1e-5f
#define NSCAN 112      // NN / 1024

typedef unsigned short u16;
typedef short bf16x8 __attribute__((ext_vector_type(8)));
typedef float f32x4 __attribute__((ext_vector_type(4)));
typedef _Float16 h8t __attribute__((ext_vector_type(8)));
typedef unsigned short u16x8 __attribute__((ext_vector_type(8)));

__device__ __forceinline__ float bf2f(u16 u) {
    union { unsigned int i; float f; } v; v.i = ((unsigned int)u) << 16; return v.f;
}
__device__ __forceinline__ u16 f2bf(float f) {
    union { float f; unsigned int i; } v; v.f = f;
    unsigned int i = v.i;
    unsigned int r = i + 0x7FFFu + ((i >> 16) & 1u);   // RNE
    return (u16)(r >> 16);
}
__device__ __forceinline__ void splitbf(float y, u16& h, u16& l) {
    h = f2bf(y);
    l = f2bf(y - bf2f(h));
}

// ---------------- graph preprocessing ----------------
__global__ __launch_bounds__(256) void k_hist(const int* __restrict__ ei, int* __restrict__ counts) {
    int e = blockIdx.x * 256 + threadIdx.x;
    atomicAdd(&counts[ei[NE + e]], 1);
}

__global__ __launch_bounds__(256) void k_scan1(const int* __restrict__ counts, int* __restrict__ bsum) {
    __shared__ int red[256];
    int tid = threadIdx.x;
    int base = blockIdx.x * 1024 + tid * 4;
    int s = counts[base] + counts[base + 1] + counts[base + 2] + counts[base + 3];
    red[tid] = s; __syncthreads();
    for (int o = 128; o > 0; o >>= 1) {
        if (tid < o) red[tid] += red[tid + o];
        __syncthreads();
    }
    if (tid == 0) bsum[blockIdx.x] = red[0];
}

__global__ void k_scan2(int* bsum, int* offs) {
    if (threadIdx.x == 0) {
        int run = 0;
        for (int i = 0; i < NSCAN; i++) { int t = bsum[i]; bsum[i] = run; run += t; }
        offs[NN] = run;
    }
}

__global__ __launch_bounds__(256) void k_scan3(const int* __restrict__ counts, const int* __restrict__ bsum,
                                               int* __restrict__ offs) {
    __shared__ int ss[256];
    int tid = threadIdx.x;
    int base = blockIdx.x * 1024 + tid * 4;
    int v0 = counts[base], v1 = counts[base + 1], v2 = counts[base + 2], v3 = counts[base + 3];
    int ts = v0 + v1 + v2 + v3;
    ss[tid] = ts; __syncthreads();
    for (int o = 1; o < 256; o <<= 1) {
        int add = (tid >= o) ? ss[tid - o] : 0;
        __syncthreads();
        ss[tid] += add;
        __syncthreads();
    }
    int excl = ss[tid] - ts + bsum[blockIdx.x];
    offs[base] = excl;
    offs[base + 1] = excl + v0;
    offs[base + 2] = excl + v0 + v1;
    offs[base + 3] = excl + v0 + v1 + v2;
}

__global__ __launch_bounds__(256) void k_dis_cursor(const int* __restrict__ counts, const int* __restrict__ offs,
                                                    float* __restrict__ dis, int* __restrict__ cursor) {
    int n = blockIdx.x * 256 + threadIdx.x;
    dis[n] = rsqrtf((float)counts[n] + 1.0f);
    cursor[n] = offs[n];
}

// scatter edges into CSR; also accumulate wsa[d] = sum_e dis[src] (for the agg-commute fold)
__global__ __launch_bounds__(256) void k_scatter(const int* __restrict__ ei, int* __restrict__ cursor,
                                                 int* __restrict__ srcs, float* __restrict__ sd,
                                                 const float* __restrict__ dis, float* __restrict__ wsa) {
    int e = blockIdx.x * 256 + threadIdx.x;
    int d = ei[NE + e], s = ei[e];
    int p = atomicAdd(&cursor[d], 1);
    float w = dis[s];
    srcs[p] = s;
    sd[p] = w;
    atomicAdd(&wsa[d], w);
}

// transpose + split fp32 W[K,F] -> bf16 Wh/Wl [F,K] (no affine; layer 1)
__global__ __launch_bounds__(256) void k_tsplit(const float* __restrict__ Wsrc,
                                                u16* __restrict__ Wh, u16* __restrict__ Wl,
                                                int K, int F) {
    int i = blockIdx.x * 256 + threadIdx.x;
    if (i < K * F) {
        int k = i / F, f = i % F;
        u16 h, l; splitbf(Wsrc[i], h, l);
        Wh[f * K + k] = h;
        Wl[f * K + k] = l;
    }
}

// PARALLEL BN-fold, part 1: Wh/Wl[f,k] = split(sc[k]*W[k,f]) — one thread per element
__global__ __launch_bounds__(256) void k_wsplit(const float* __restrict__ W, const float* __restrict__ sc,
                                                u16* __restrict__ Wh, u16* __restrict__ Wl,
                                                int K, int F) {
    int i = blockIdx.x * 256 + threadIdx.x;
    if (i < K * F) {
        int k = i / F, f = i % F;
        u16 h, l; splitbf(sc[k] * W[i], h, l);
        Wh[f * K + k] = h;
        Wl[f * K + k] = l;
    }
}

// PARALLEL BN-fold, part 2: c2[f] = sum_k sh[k]*W[k,f] — one wave per column
__global__ __launch_bounds__(256) void k_wc2(const float* __restrict__ W, const float* __restrict__ sh,
                                             float* __restrict__ c2, int K, int F) {
    int wv = (blockIdx.x * 256 + threadIdx.x) >> 6;
    int lane = threadIdx.x & 63;
    if (wv >= F) return;
    float acc = 0.f;
    for (int k = lane; k < K; k += 64) acc += sh[k] * W[k * F + wv];
#pragma unroll
    for (int o = 1; o < 64; o <<= 1) acc += __shfl_xor(acc, o);
    if (lane == 0) c2[wv] = acc;
}

// ---------------- split MFMA GEMM: C = A @ W' (+epilogues), fp32-grade via bf16x3 ----------------
// AFP32: A is fp32 (layer 1, split at stage). Else A is two exact bf16 planes Ahi/Alo [N][K].
// W pre-split (+BN-folded) bf16 hi/lo [Fout][K]. C2: init acc with per-column constant. C fp16.
// TEPI (layer-2 agg-commute epilogue): v = acc + wsum[row]*c2[col] + bias[col]; t = relu(v);
//   write exact bf16 hi/lo planes Thi/Tlo and accumulate per-column BN stats into Sg/Qg.
template<int BM, int BN, int WCOLS, bool AFP32, bool C2, bool TEPI>
__global__ __launch_bounds__(256) void k_gemm(
    const float* __restrict__ Af, const u16* __restrict__ Ahi, const u16* __restrict__ Alo,
    const u16* __restrict__ Wh, const u16* __restrict__ Wl,
    _Float16* __restrict__ C, const int K, const int Fout, const float* __restrict__ c2,
    const float* __restrict__ bias, const float* __restrict__ wsa, const float* __restrict__ disv,
    u16* __restrict__ Thi, u16* __restrict__ Tlo, float* __restrict__ Sg, float* __restrict__ Qg)
{
    constexpr int AST = 40;                // 32 + 8 pad
    __shared__ u16 Ah[BM][AST], Al[BM][AST];
    __shared__ u16 Bh[BN][AST], Bl[BN][AST];
    __shared__ float redS[TEPI ? BN : 1], redQ[TEPI ? BN : 1];

    const int tid = threadIdx.x;
    const int row0 = blockIdx.y * BM;
    const int col0 = blockIdx.x * BN;

    const int wave = tid >> 6, lane = tid & 63;
    const int mb = (wave / WCOLS) * 64;
    const int nb = (wave % WCOLS) * 64;
    const int lm = lane & 15;
    const int lk = (lane >> 4) * 8;
    const int cb = col0 + nb + lm;

    if constexpr (TEPI) {
        for (int i = tid; i < BN; i += 256) { redS[i] = 0.f; redQ[i] = 0.f; }
    }

    float c2v[4] = {0.f, 0.f, 0.f, 0.f};
    if constexpr (C2) {
#pragma unroll
        for (int ni = 0; ni < 4; ni++) c2v[ni] = c2[cb + ni * 16];
    }

    f32x4 acc[4][4];
#pragma unroll
    for (int i = 0; i < 4; i++)
#pragma unroll
        for (int j = 0; j < 4; j++)
#pragma unroll
            for (int r = 0; r < 4; r++) acc[i][j][r] = c2v[j];

    const int stg_r = tid >> 3;        // 0..31
    const int stg_c = (tid & 7) * 4;   // 0,4..28

    for (int k0 = 0; k0 < K; k0 += 32) {
        __syncthreads();
#pragma unroll
        for (int p = 0; p < BM / 32; p++) {
            const int r = p * 32 + stg_r;
            if constexpr (AFP32) {
                const float4 v = *(const float4*)(Af + (size_t)(row0 + r) * K + k0 + stg_c);
                float y[4] = {v.x, v.y, v.z, v.w};
                ushort4 hv, lv;
#pragma unroll
                for (int q = 0; q < 4; q++) splitbf(y[q], ((u16*)&hv)[q], ((u16*)&lv)[q]);
                *(ushort4*)&Ah[r][stg_c] = hv;
                *(ushort4*)&Al[r][stg_c] = lv;
            } else {
                *(ushort4*)&Ah[r][stg_c] = *(const ushort4*)(Ahi + (size_t)(row0 + r) * K + k0 + stg_c);
                *(ushort4*)&Al[r][stg_c] = *(const ushort4*)(Alo + (size_t)(row0 + r) * K + k0 + stg_c);
            }
        }
#pragma unroll
        for (int p = 0; p < BN / 32; p++) {
            const int n = p * 32 + stg_r;
            *(ushort4*)&Bh[n][stg_c] = *(const ushort4*)(Wh + (size_t)(col0 + n) * K + k0 + stg_c);
            *(ushort4*)&Bl[n][stg_c] = *(const ushort4*)(Wl + (size_t)(col0 + n) * K + k0 + stg_c);
        }
        __syncthreads();

        bf16x8 ah[4], al[4], bh[4], bl[4];
#pragma unroll
        for (int mi = 0; mi < 4; mi++) {
            ah[mi] = *(const bf16x8*)&Ah[mb + mi * 16 + lm][lk];
            al[mi] = *(const bf16x8*)&Al[mb + mi * 16 + lm][lk];
        }
#pragma unroll
        for (int ni = 0; ni < 4; ni++) {
            bh[ni] = *(const bf16x8*)&Bh[nb + ni * 16 + lm][lk];
            bl[ni] = *(const bf16x8*)&Bl[nb + ni * 16 + lm][lk];
        }
#pragma unroll
        for (int mi = 0; mi < 4; mi++)
#pragma unroll
            for (int ni = 0; ni < 4; ni++) {
                acc[mi][ni] = __builtin_amdgcn_mfma_f32_16x16x32_bf16(al[mi], bh[ni], acc[mi][ni], 0, 0, 0);
                acc[mi][ni] = __builtin_amdgcn_mfma_f32_16x16x32_bf16(ah[mi], bl[ni], acc[mi][ni], 0, 0, 0);
                acc[mi][ni] = __builtin_amdgcn_mfma_f32_16x16x32_bf16(ah[mi], bh[ni], acc[mi][ni], 0, 0, 0);
            }
    }

    const int rb = row0 + mb + (lane >> 4) * 4;
    if constexpr (TEPI) {
        float c2l[4], bl4[4];
#pragma unroll
        for (int ni = 0; ni < 4; ni++) { c2l[ni] = c2[cb + ni * 16]; bl4[ni] = bias[cb + ni * 16]; }
        float ws[4][4];
#pragma unroll
        for (int mi = 0; mi < 4; mi++)
#pragma unroll
            for (int r = 0; r < 4; r++) {
                const int row = rb + mi * 16 + r;
                const float d = disv[row];
                ws[mi][r] = d * wsa[row] + d * d;
            }
#pragma unroll
        for (int ni = 0; ni < 4; ni++) {
            float s = 0.f, q = 0.f;
#pragma unroll
            for (int mi = 0; mi < 4; mi++)
#pragma unroll
                for (int r = 0; r < 4; r++) {
                    float v = acc[mi][ni][r] + ws[mi][r] * c2l[ni] + bl4[ni];
                    v = fmaxf(v, 0.f);
                    s += v; q += v * v;
                    u16 hh, ll; splitbf(v, hh, ll);
                    const size_t idx = (size_t)(rb + mi * 16 + r) * Fout + cb + ni * 16;
                    Thi[idx] = hh;
                    Tlo[idx] = ll;
                }
            atomicAdd(&redS[nb + ni * 16 + lm], s);
            atomicAdd(&redQ[nb + ni * 16 + lm], q);
        }
        __syncthreads();
        for (int i = tid; i < BN; i += 256) {
            atomicAdd(&Sg[col0 + i], redS[i]);
            atomicAdd(&Qg[col0 + i], redQ[i]);
        }
    } else {
#pragma unroll
        for (int mi = 0; mi < 4; mi++)
#pragma unroll
            for (int ni = 0; ni < 4; ni++)
#pragma unroll
                for (int r = 0; r < 4; r++)
                    C[(size_t)(rb + mi * 16 + r) * Fout + cb + ni * 16] = (_Float16)acc[mi][ni][r];
    }
}

// ---------------- aggregation: t = relu(dn*sum(sd_e*h_s) + dn^2*h_n + b), fused BN stats --------
// ONE NODE PER LANE-GROUP (LPG lanes), serial edge loop -> ZERO per-node cross-lane merges.
// h fp16 [N][CH]. FP16OUT: write t as fp16 single plane. Else exact bf16 hi/lo planes.
// BN stats held per-lane; merged across groups ONCE per wave at the end.
template<int CH, bool FP16OUT>
__global__ __launch_bounds__(256) void k_agg(
    const _Float16* __restrict__ h, u16* __restrict__ thi, u16* __restrict__ tlo,
    const float* __restrict__ bias,
    const int* __restrict__ off, const int* __restrict__ srcs, const float* __restrict__ sd,
    const float* __restrict__ dis, float* __restrict__ statS, float* __restrict__ statQ,
    _Float16* __restrict__ tf)
{
    constexpr int ECH = 16;            // channels per lane (32B fp16)
    constexpr int LPG = CH / ECH;      // lanes per node
    constexpr int G   = 64 / LPG;      // nodes per wave
    constexpr int NB  = NN / G;        // node batches
    __shared__ float redS[CH], redQ[CH];
    const int tid = threadIdx.x;
    for (int i = tid; i < CH; i += 256) { redS[i] = 0.f; redQ[i] = 0.f; }
    __syncthreads();

    const int lane = tid & 63;
    const int g = lane / LPG;          // node slot within wave
    const int c = (lane % LPG) * ECH;  // channel offset
    const int wid = (blockIdx.x * 256 + tid) >> 6;
    const int nw = (gridDim.x * 256) >> 6;

    float bs[ECH], bq[ECH], bv[ECH];
#pragma unroll
    for (int v = 0; v < ECH; v++) { bs[v] = 0.f; bq[v] = 0.f; bv[v] = bias[c + v]; }

    for (int b = wid; b < NB; b += nw) {
        const int n = b * G + g;
        const int p0 = off[n], p1 = off[n + 1];
        float a[ECH];
#pragma unroll
        for (int v = 0; v < ECH; v++) a[v] = 0.f;

        int p = p0;
        int s = 0; float w = 0.f;
        if (p < p1) { s = srcs[p]; w = sd[p]; }
        while (p < p1) {
            int s2 = 0; float w2 = 0.f;
            if (p + 1 < p1) { s2 = srcs[p + 1]; w2 = sd[p + 1]; }   // prefetch next edge
            const _Float16* hr = h + (size_t)s * CH + c;
            h8t hv0 = *(const h8t*)hr;
            h8t hv1 = *(const h8t*)(hr + 8);
#pragma unroll
            for (int v = 0; v < 8; v++) { a[v] += w * (float)hv0[v]; a[v + 8] += w * (float)hv1[v]; }
            s = s2; w = w2; ++p;
        }
        // no cross-lane merge needed: this lane owns channels c..c+15 of node n
        const float dn = dis[n];
        const float dn2 = dn * dn;
        const _Float16* hr = h + (size_t)n * CH + c;
        h8t hn0 = *(const h8t*)hr;
        h8t hn1 = *(const h8t*)(hr + 8);
        float o16[ECH];
#pragma unroll
        for (int v = 0; v < 8; v++) {
            o16[v] = fmaxf(dn * a[v] + dn2 * (float)hn0[v] + bv[v], 0.f);
            o16[v + 8] = fmaxf(dn * a[v + 8] + dn2 * (float)hn1[v] + bv[v + 8], 0.f);
        }
#pragma unroll
        for (int v = 0; v < ECH; v++) { bs[v] += o16[v]; bq[v] += o16[v] * o16[v]; }
        if constexpr (FP16OUT) {
            h8t o0, o1;
#pragma unroll
            for (int v = 0; v < 8; v++) { o0[v] = (_Float16)o16[v]; o1[v] = (_Float16)o16[v + 8]; }
            _Float16* tr = tf + (size_t)n * CH + c;
            *(h8t*)tr = o0; *(h8t*)(tr + 8) = o1;
        } else {
            u16x8 hv0, lv0, hv1, lv1;
#pragma unroll
            for (int v = 0; v < 8; v++) {
                splitbf(o16[v], ((u16*)&hv0)[v], ((u16*)&lv0)[v]);
                splitbf(o16[v + 8], ((u16*)&hv1)[v], ((u16*)&lv1)[v]);
            }
            u16* th = thi + (size_t)n * CH + c;
            u16* tl = tlo + (size_t)n * CH + c;
            *(u16x8*)th = hv0; *(u16x8*)(th + 8) = hv1;
            *(u16x8*)tl = lv0; *(u16x8*)(tl + 8) = lv1;
        }
    }
    // one-time stats merge across the G node-slots of this wave
#pragma unroll
    for (int o = LPG; o < 64; o <<= 1) {
#pragma unroll
        for (int v = 0; v < ECH; v++) { bs[v] += __shfl_xor(bs[v], o); bq[v] += __shfl_xor(bq[v], o); }
    }
    if (g == 0) {
#pragma unroll
        for (int v = 0; v < ECH; v++) { atomicAdd(&redS[c + v], bs[v]); atomicAdd(&redQ[c + v], bq[v]); }
    }
    __syncthreads();
    for (int i = tid; i < CH; i += 256) { atomicAdd(&statS[i], redS[i]); atomicAdd(&statQ[i], redQ[i]); }
}

// ---------------- pure linear aggregation: u = dn*sum(sd_e*t_s) + dn^2*t_n ----------------
// Same node-per-lane-group structure (no shuffles). t fp16 [N][CH]; u -> exact bf16 hi/lo planes.
template<int CH>
__global__ __launch_bounds__(256) void k_agglin(
    const _Float16* __restrict__ t, u16* __restrict__ uhi, u16* __restrict__ ulo,
    const int* __restrict__ off, const int* __restrict__ srcs, const float* __restrict__ sd,
    const float* __restrict__ dis)
{
    constexpr int ECH = 16;
    constexpr int LPG = CH / ECH;
    constexpr int G   = 64 / LPG;
    constexpr int NB  = NN / G;
    const int tid = threadIdx.x;
    const int lane = tid & 63;
    const int g = lane / LPG;
    const int c = (lane % LPG) * ECH;
    const int wid = (blockIdx.x * 256 + tid) >> 6;
    const int nw = (gridDim.x * 256) >> 6;

    for (int b = wid; b < NB; b += nw) {
        const int n = b * G + g;
        const int p0 = off[n], p1 = off[n + 1];
        float a[ECH];
#pragma unroll
        for (int v = 0; v < ECH; v++) a[v] = 0.f;

        int p = p0;
        int s = 0; float w = 0.f;
        if (p < p1) { s = srcs[p]; w = sd[p]; }
        while (p < p1) {
            int s2 = 0; float w2 = 0.f;
            if (p + 1 < p1) { s2 = srcs[p + 1]; w2 = sd[p + 1]; }
            const _Float16* hr = t + (size_t)s * CH + c;
            h8t hv0 = *(const h8t*)hr;
            h8t hv1 = *(const h8t*)(hr + 8);
#pragma unroll
            for (int v = 0; v < 8; v++) { a[v] += w * (float)hv0[v]; a[v + 8] += w * (float)hv1[v]; }
            s = s2; w = w2; ++p;
        }
        const float dn = dis[n];
        const float dn2 = dn * dn;
        const _Float16* hr = t + (size_t)n * CH + c;
        h8t hn0 = *(const h8t*)hr;
        h8t hn1 = *(const h8t*)(hr + 8);
        u16x8 hv0, lv0, hv1, lv1;
#pragma unroll
        for (int v = 0; v < 8; v++) {
            float o0 = dn * a[v] + dn2 * (float)hn0[v];
            float o1 = dn * a[v + 8] + dn2 * (float)hn1[v];
            splitbf(o0, ((u16*)&hv0)[v], ((u16*)&lv0)[v]);
            splitbf(o1, ((u16*)&hv1)[v], ((u16*)&lv1)[v]);
        }
        u16* th = uhi + (size_t)n * CH + c;
        u16* tl = ulo + (size_t)n * CH + c;
        *(u16x8*)th = hv0; *(u16x8*)(th + 8) = hv1;
        *(u16x8*)tl = lv0; *(u16x8*)(tl + 8) = lv1;
    }
}

// ---------------- BN stats -> scale/shift ----------------
__global__ void k_bnpar(const float* __restrict__ S, const float* __restrict__ Q,
                        const float* __restrict__ g, const float* __restrict__ b,
                        float* __restrict__ sc, float* __restrict__ sh, int F) {
    int c = threadIdx.x;
    if (c >= F) return;
    const float invn = 1.0f / (float)NN;
    float mean = S[c] * invn;
    float var = Q[c] * invn - mean * mean;
    float s = g[c] * rsqrtf(fmaxf(var, 0.f) + EPSB);
    sc[c] = s;
    sh[c] = b[c] - mean * s;
}

// ---------------- small dense layer: C[N,F] = affine(A)[N,K] @ W[K,F] (+bias) ----------------
// A = bf16 hi/lo planes, C fp16, fp32 compute. STATS: fused per-column sum/sumsq of acc.
template<int K, int F, bool BIAS, bool STATS>
__global__ __launch_bounds__(256) void k_smm(
    const u16* __restrict__ Ahi, const u16* __restrict__ Alo,
    const float* __restrict__ Wf, const float* __restrict__ bias,
    _Float16* __restrict__ C, const float* __restrict__ sc, const float* __restrict__ sh,
    float* __restrict__ Sg, float* __restrict__ Qg)
{
    __shared__ float Wl[K * F];
    __shared__ float scl[K], shl[K], bl[F];
    __shared__ float redS[F], redQ[F];
    const int tid = threadIdx.x;
    for (int i = tid; i < K * F; i += 256) Wl[i] = Wf[i];
    if (tid < K) { scl[tid] = sc[tid]; shl[tid] = sh[tid]; }
    if (tid < F) {
        bl[tid] = 0.f;
        if constexpr (BIAS) bl[tid] = bias[tid];
        if constexpr (STATS) { redS[tid] = 0.f; redQ[tid] = 0.f; }
    }
    __syncthreads();
    const int n = blockIdx.x * 256 + tid;
    float acc[F];
#pragma unroll
    for (int f = 0; f < F; f++) acc[f] = bl[f];
    const u16* ah = Ahi + (size_t)n * K;
    const u16* al = Alo + (size_t)n * K;
    for (int k = 0; k < K; k += 4) {
        ushort4 hv = *(const ushort4*)(ah + k);
        ushort4 lv = *(const ushort4*)(al + k);
        float y0 = (bf2f(hv.x) + bf2f(lv.x)) * scl[k] + shl[k];
        float y1 = (bf2f(hv.y) + bf2f(lv.y)) * scl[k + 1] + shl[k + 1];
        float y2 = (bf2f(hv.z) + bf2f(lv.z)) * scl[k + 2] + shl[k + 2];
        float y3 = (bf2f(hv.w) + bf2f(lv.w)) * scl[k + 3] + shl[k + 3];
#pragma unroll
        for (int f = 0; f < F; f += 4) {
            float4 w0 = *(const float4*)&Wl[k * F + f];
            float4 w1 = *(const float4*)&Wl[(k + 1) * F + f];
            float4 w2 = *(const float4*)&Wl[(k + 2) * F + f];
            float4 w3 = *(const float4*)&Wl[(k + 3) * F + f];
            acc[f + 0] += y0 * w0.x + y1 * w1.x + y2 * w2.x + y3 * w3.x;
            acc[f + 1] += y0 * w0.y + y1 * w1.y + y2 * w2.y + y3 * w3.y;
            acc[f + 2] += y0 * w0.z + y1 * w1.z + y2 * w2.z + y3 * w3.z;
            acc[f + 3] += y0 * w0.w + y1 * w1.w + y2 * w2.w + y3 * w3.w;
        }
    }
    _Float16* cr = C + (size_t)n * F;
#pragma unroll
    for (int f = 0; f < F; f++) cr[f] = (_Float16)acc[f];
    if constexpr (STATS) {
        float s[F], q[F];
#pragma unroll
        for (int f = 0; f < F; f++) { s[f] = acc[f]; q[f] = acc[f] * acc[f]; }
#pragma unroll
        for (int o = 1; o < 64; o <<= 1) {
#pragma unroll
            for (int f = 0; f < F; f++) { s[f] += __shfl_xor(s[f], o); q[f] += __shfl_xor(q[f], o); }
        }
        if ((tid & 63) == 0) {
#pragma unroll
            for (int f = 0; f < F; f++) { atomicAdd(&redS[f], s[f]); atomicAdd(&redQ[f], q[f]); }
        }
        __syncthreads();
        for (int i = tid; i < F; i += 256) { atomicAdd(&Sg[i], redS[i]); atomicAdd(&Qg[i], redQ[i]); }
    }
}

// ---------------- gate layer 2: g2 = relu(bn1(g1)) @ gW2 + gb2, fused scalar stats ----------------
__global__ __launch_bounds__(256) void k_gate2(const _Float16* __restrict__ g1,
                                               const float* __restrict__ sc, const float* __restrict__ sh,
                                               const float* __restrict__ w2, const float* __restrict__ b2,
                                               float* __restrict__ g2,
                                               float* __restrict__ Sg, float* __restrict__ Qg) {
    __shared__ float wl[16], scl[16], shl[16], b2l[1];
    __shared__ float redSg[1], redQg[1];
    const int tid = threadIdx.x;
    if (tid < 16) { wl[tid] = w2[tid]; scl[tid] = sc[tid]; shl[tid] = sh[tid]; }
    if (tid == 0) { b2l[0] = b2[0]; redSg[0] = 0.f; redQg[0] = 0.f; }
    __syncthreads();
    const int n = blockIdx.x * 256 + tid;
    const _Float16* r = g1 + (size_t)n * 16;
    float acc = b2l[0];
#pragma unroll
    for (int k = 0; k < 16; k++) {
        float y = fmaxf((float)r[k] * scl[k] + shl[k], 0.f);
        acc += y * wl[k];
    }
    g2[n] = acc;
    float s = acc, q = acc * acc;
#pragma unroll
    for (int o = 1; o < 64; o <<= 1) { s += __shfl_xor(s, o); q += __shfl_xor(q, o); }
    if ((tid & 63) == 0) { atomicAdd(&redSg[0], s); atomicAdd(&redQg[0], q); }
    __syncthreads();
    if (tid == 0) { atomicAdd(&Sg[0], redSg[0]); atomicAdd(&Qg[0], redQg[0]); }
}

// ---------------- segment softmax + pooling + FC + softmax ----------------
__global__ __launch_bounds__(256) void k_pool(const u16* __restrict__ t4hi, const u16* __restrict__ t4lo,
                                              const float* __restrict__ sc4, const float* __restrict__ sh4,
                                              const float* __restrict__ g2,
                                              const float* __restrict__ gsc2, const float* __restrict__ gsh2,
                                              const float* __restrict__ fcW, const float* __restrict__ fcb,
                                              float* __restrict__ out) {
    __shared__ float fw[32 * NCLS], fbl[NCLS], sc4l[32], sh4l[32];
    const int tid = threadIdx.x;
    for (int i = tid; i < 32 * NCLS; i += 256) fw[i] = fcW[i];
    if (tid < NCLS) fbl[tid] = fcb[tid];
    if (tid < 32) { sc4l[tid] = sc4[tid]; sh4l[tid] = sh4[tid]; }
    __syncthreads();
    const int b = blockIdx.x * 256 + tid;
    const float s2 = gsc2[0], h2 = gsh2[0];
    const int base = b * GSZ;

    float gv[GSZ];
    float m = -1e30f;
#pragma unroll
    for (int i = 0; i < GSZ; i++) {
        float v = fmaxf(g2[base + i] * s2 + h2, 0.f);
        gv[i] = v; m = fmaxf(m, v);
    }
    float ssum = 0.f;
#pragma unroll
    for (int i = 0; i < GSZ; i++) { float e = __expf(gv[i] - m); gv[i] = e; ssum += e; }
    const float inv = 1.0f / ssum;

    float pooled[32];
#pragma unroll
    for (int c = 0; c < 32; c++) pooled[c] = 0.f;
#pragma unroll
    for (int i = 0; i < GSZ; i++) {
        const float a = gv[i] * inv;
        const u16* th = t4hi + (size_t)(base + i) * 32;
        const u16* tl = t4lo + (size_t)(base + i) * 32;
#pragma unroll
        for (int c = 0; c < 32; c += 4) {
            ushort4 hv = *(const ushort4*)(th + c);
            ushort4 lv = *(const ushort4*)(tl + c);
            pooled[c + 0] += a * ((bf2f(hv.x) + bf2f(lv.x)) * sc4l[c + 0] + sh4l[c + 0]);
            pooled[c + 1] += a * ((bf2f(hv.y) + bf2f(lv.y)) * sc4l[c + 1] + sh4l[c + 1]);
            pooled[c + 2] += a * ((bf2f(hv.z) + bf2f(lv.z)) * sc4l[c + 2] + sh4l[c + 2]);
            pooled[c + 3] += a * ((bf2f(hv.w) + bf2f(lv.w)) * sc4l[c + 3] + sh4l[c + 3]);
        }
    }
    float lg[NCLS];
    float mx = -1e30f;
#pragma unroll
    for (int j = 0; j < NCLS; j++) {
        float a = fbl[j];
#pragma unroll
        for (int c = 0; c < 32; c++) a += pooled[c] * fw[c * NCLS + j];
        lg[j] = a; mx = fmaxf(mx, a);
    }
    float es = 0.f;
#pragma unroll
    for (int j = 0; j < NCLS; j++) { float e = __expf(lg[j] - mx); lg[j] = e; es += e; }
    const float iv = 1.0f / es;
#pragma unroll
    for (int j = 0; j < NCLS; j++) out[b * NCLS + j] = lg[j] * iv;
}

// ---------------- host ----------------
extern "C" void kernel_launch(void* const* d_in, const int* in_sizes, int n_in,
                              void* d_out, int out_size, void* d_ws, size_t ws_size,
                              hipStream_t stream) {
    (void)in_sizes; (void)n_in; (void)out_size; (void)ws_size;
    const float* x    = (const float*)d_in[0];
    const int*   ei   = (const int*)d_in[1];
    const float* W1   = (const float*)d_in[2];
    const float* b1   = (const float*)d_in[3];
    const float* bn1g = (const float*)d_in[4];
    const float* bn1b = (const float*)d_in[5];
    const float* W2   = (const float*)d_in[6];
    const float* b2   = (const float*)d_in[7];
    const float* bn2g = (const float*)d_in[8];
    const float* bn2b = (const float*)d_in[9];
    const float* W3   = (const float*)d_in[10];
    const float* b3   = (const float*)d_in[11];
    const float* bn3g = (const float*)d_in[12];
    const float* bn3b = (const float*)d_in[13];
    const float* W4   = (const float*)d_in[14];
    const float* b4   = (const float*)d_in[15];
    const float* bn4g = (const float*)d_in[16];
    const float* bn4b = (const float*)d_in[17];
    const float* gW1  = (const float*)d_in[18];
    const float* gb1  = (const float*)d_in[19];
    const float* gbn1g = (const float*)d_in[20];
    const float* gbn1b = (const float*)d_in[21];
    const float* gW2  = (const float*)d_in[22];
    const float* gb2  = (const float*)d_in[23];
    const float* gbn2g = (const float*)d_in[24];
    const float* gbn2b = (const float*)d_in[25];
    const float* fcW  = (const float*)d_in[26];
    const float* fcb  = (const float*)d_in[27];
    float* out = (float*)d_out;

    char* base = (char*)d_ws;
    size_t off_ = 0;
    auto carve = [&](size_t bytes) -> char* {
        char* p = base + off_;
        off_ = (off_ + bytes + 255) & ~(size_t)255;
        return p;
    };
    int*   counts = (int*)carve((size_t)NN * 4);
    float* stats  = (float*)carve(994 * 4);
    float* wsa    = (float*)carve((size_t)NN * 4);
    const size_t zero_bytes = off_;
    int*   offs   = (int*)carve((size_t)(NN + 1) * 4);
    int*   cursor = (int*)carve((size_t)NN * 4);
    int*   srcs   = (int*)carve((size_t)NE * 4);
    float* sd     = (float*)carve((size_t)NE * 4);
    float* dis    = (float*)carve((size_t)NN * 4);
    int*   bsum   = (int*)carve(NSCAN * 4);
    float* pars   = (float*)carve(994 * 4);
    u16*   Wt1h   = (u16*)carve(512 * 128 * 2);
    u16*   Wt1l   = (u16*)carve(512 * 128 * 2);
    u16*   Wt2h   = (u16*)carve(128 * 256 * 2);
    u16*   Wt2l   = (u16*)carve(128 * 256 * 2);
    u16*   Wt3h   = (u16*)carve(256 * 64 * 2);
    u16*   Wt3l   = (u16*)carve(256 * 64 * 2);
    float* c2_2   = (float*)carve(256 * 4);
    float* c2_3   = (float*)carve(64 * 4);
    float* g2raw  = (float*)carve((size_t)NN * 4);
    _Float16* P   = (_Float16*)carve((size_t)NN * 256 * 2);   // h buffer (fp16, up to 256 ch)
    u16*   Qhi    = (u16*)carve((size_t)NN * 128 * 2);        // t/u planes (<=128 ch)
    u16*   Qlo    = (u16*)carve((size_t)NN * 128 * 2);
    u16*   Rhi    = (u16*)carve((size_t)NN * 256 * 2);        // t2 planes (256 ch)
    u16*   Rlo    = (u16*)carve((size_t)NN * 256 * 2);
    // t1 fp16 single plane lives in the upper half of P (h1 only uses [N,128])
    _Float16* T1f = P + (size_t)NN * 128;

    float* S1 = stats;      float* Q1s = S1 + 128;
    float* S2 = Q1s + 128;  float* Q2s = S2 + 256;
    float* S3 = Q2s + 256;  float* Q3s = S3 + 64;
    float* S4 = Q3s + 64;   float* Q4s = S4 + 32;
    float* gS1 = Q4s + 32;  float* gQ1 = gS1 + 16;
    float* gS2 = gQ1 + 16;  float* gQ2 = gS2 + 1;

    float* sc1 = pars;      float* sh1 = sc1 + 128;
    float* sc2 = sh1 + 128; float* sh2 = sc2 + 256;
    float* sc3 = sh2 + 256; float* sh3 = sc3 + 64;
    float* sc4 = sh3 + 64;  float* sh4 = sc4 + 32;
    float* gsc1 = sh4 + 32; float* gsh1 = gsc1 + 16;
    float* gsc2 = gsh1 + 16; float* gsh2 = gsc2 + 1;

    hipMemsetAsync(d_ws, 0, zero_bytes, stream);

    k_hist<<<NE / 256, 256, 0, stream>>>(ei, counts);
    k_scan1<<<NSCAN, 256, 0, stream>>>(counts, bsum);
    k_scan2<<<1, 64, 0, stream>>>(bsum, offs);
    k_scan3<<<NSCAN, 256, 0, stream>>>(counts, bsum, offs);
    k_dis_cursor<<<NN / 256, 256, 0, stream>>>(counts, offs, dis, cursor);
    k_scatter<<<NE / 256, 256, 0, stream>>>(ei, cursor, srcs, sd, dis, wsa);
    k_tsplit<<<(512 * 128 + 255) / 256, 256, 0, stream>>>(W1, Wt1h, Wt1l, 512, 128);

    // layer 1: h1 = x @ W1 -> P (N x 128 fp16); t1 = relu(agg(h1)+b1) -> T1f fp16 + BN1 stats
    k_gemm<128, 128, 2, true, false, false><<<dim3(1, NN / 128), 256, 0, stream>>>(
        x, nullptr, nullptr, Wt1h, Wt1l, P, 512, 128, nullptr,
        nullptr, nullptr, nullptr, nullptr, nullptr, nullptr, nullptr);
    k_agg<128, true><<<1792, 256, 0, stream>>>(P, nullptr, nullptr, b1, offs, srcs, sd, dis, S1, Q1s, T1f);
    k_bnpar<<<1, 256, 0, stream>>>(S1, Q1s, bn1g, bn1b, sc1, sh1, 128);

    // layer 2, agg-commute: u = agg(t1) on 128 ch -> Q planes; then
    // t2 = relu(u@(sc1*W2) + wsum*(sh1@W2) + b2) in the GEMM epilogue -> R planes + BN2 stats
    k_agglin<128><<<1792, 256, 0, stream>>>(T1f, Qhi, Qlo, offs, srcs, sd, dis);
    k_wsplit<<<(128 * 256 + 255) / 256, 256, 0, stream>>>(W2, sc1, Wt2h, Wt2l, 128, 256);
    k_wc2<<<(256 * 64 + 255) / 256, 256, 0, stream>>>(W2, sh1, c2_2, 128, 256);
    k_gemm<128, 128, 2, false, false, true><<<dim3(2, NN / 128), 256, 0, stream>>>(
        nullptr, Qhi, Qlo, Wt2h, Wt2l, nullptr, 128, 256, c2_2,
        b2, wsa, dis, Rhi, Rlo, S2, Q2s);
    k_bnpar<<<1, 256, 0, stream>>>(S2, Q2s, bn2g, bn2b, sc2, sh2, 256);

    // layer 3 (BN folded into W3): h3 = t2 @ W3' + c2 -> P (N x 64); t3 -> Q planes
    k_wsplit<<<(256 * 64 + 255) / 256, 256, 0, stream>>>(W3, sc2, Wt3h, Wt3l, 256, 64);
    k_wc2<<<(64 * 64 + 255) / 256, 256, 0, stream>>>(W3, sh2, c2_3, 256, 64);
    k_gemm<256, 64, 1, false, true, false><<<dim3(1, NN / 256), 256, 0, stream>>>(
        nullptr, Rhi, Rlo, Wt3h, Wt3l, P, 256, 64, c2_3,
        nullptr, nullptr, nullptr, nullptr, nullptr, nullptr, nullptr);
    k_agg<64, false><<<1792, 256, 0, stream>>>(P, Qhi, Qlo, b3, offs, srcs, sd, dis, S3, Q3s, nullptr);
    k_bnpar<<<1, 256, 0, stream>>>(S3, Q3s, bn3g, bn3b, sc3, sh3, 64);

    // layer 4: h4 = bn(t3) @ W4 -> P (N x 32 fp16); t4 -> Q planes (32 ch)
    k_smm<64, 32, false, false><<<NN / 256, 256, 0, stream>>>(Qhi, Qlo, W4, nullptr, P, sc3, sh3,
                                                              nullptr, nullptr);
    k_agg<32, false><<<896, 256, 0, stream>>>(P, Qhi, Qlo, b4, offs, srcs, sd, dis, S4, Q4s, nullptr);
    k_bnpar<<<1, 256, 0, stream>>>(S4, Q4s, bn4g, bn4b, sc4, sh4, 32);

    // gate 1: g1 = bn4(t4) @ gW1 + gb1 -> P (N x 16 fp16), stats fused
    k_smm<32, 16, true, true><<<NN / 256, 256, 0, stream>>>(Qhi, Qlo, gW1, gb1, P, sc4, sh4, gS1, gQ1);
    k_bnpar<<<1, 256, 0, stream>>>(gS1, gQ1, gbn1g, gbn1b, gsc1, gsh1, 16);

    // gate 2: g2 = relu(bn(g1)) @ gW2 + gb2 -> g2raw (N, fp32), stats fused
    k_gate2<<<NN / 256, 256, 0, stream>>>(P, gsc1, gsh1, gW2, gb2, g2raw, gS2, gQ2);
    k_bnpar<<<1, 256, 0, stream>>>(gS2, gQ2, gbn2g, gbn2b, gsc2, gsh2, 1);

    // pooling + FC + softmax
    k_pool<<<NBATCH / 256, 256, 0, stream>>>(Qhi, Qlo, sc4, sh4, g2raw, gsc2, gsh2, fcW, fcb, out);
}

// Round 6
// 956.650 us; speedup vs baseline: 1.1965x; 1.0191x over previous
//
#include <hip/hip_runtime.h>

#define NN 114688      // nodes
#define NE 917504      // edges
#define NBATCH 8192    // graphs
#define GSZ 14         // nodes per graph
#define NCLS 10
#define EPSB 1e-5f
#define NSCAN 112      // NN / 1024

typedef unsigned short u16;
typedef short bf16x8 __attribute__((ext_vector_type(8)));
typedef float f32x4 __attribute__((ext_vector_type(4)));
typedef _Float16 h8t __attribute__((ext_vector_type(8)));
typedef unsigned short u16x8 __attribute__((ext_vector_type(8)));

__device__ __forceinline__ float bf2f(u16 u) {
    union { unsigned int i; float f; } v; v.i = ((unsigned int)u) << 16; return v.f;
}
__device__ __forceinline__ u16 f2bf(float f) {
    union { float f; unsigned int i; } v; v.f = f;
    unsigned int i = v.i;
    unsigned int r = i + 0x7FFFu + ((i >> 16) & 1u);   // RNE
    return (u16)(r >> 16);
}
__device__ __forceinline__ void splitbf(float y, u16& h, u16& l) {
    h = f2bf(y);
    l = f2bf(y - bf2f(h));
}
// BN scale/shift from raw stats — folded into every consumer (replaces k_bnpar launches)
__device__ __forceinline__ void bnparams(const float* __restrict__ S, const float* __restrict__ Q,
                                         const float* __restrict__ g, const float* __restrict__ b,
                                         int c, float& sc, float& sh) {
    const float invn = 1.0f / (float)NN;
    float mean = S[c] * invn;
    float var = Q[c] * invn - mean * mean;
    float s = g[c] * rsqrtf(fmaxf(var, 0.f) + EPSB);
    sc = s;
    sh = b[c] - mean * s;
}

// ---------------- graph preprocessing ----------------
__global__ __launch_bounds__(256) void k_hist(const int* __restrict__ ei, int* __restrict__ counts) {
    int e = blockIdx.x * 256 + threadIdx.x;
    atomicAdd(&counts[ei[NE + e]], 1);
}

__global__ __launch_bounds__(256) void k_scan1(const int* __restrict__ counts, int* __restrict__ bsum) {
    __shared__ int red[256];
    int tid = threadIdx.x;
    int base = blockIdx.x * 1024 + tid * 4;
    int s = counts[base] + counts[base + 1] + counts[base + 2] + counts[base + 3];
    red[tid] = s; __syncthreads();
    for (int o = 128; o > 0; o >>= 1) {
        if (tid < o) red[tid] += red[tid + o];
        __syncthreads();
    }
    if (tid == 0) bsum[blockIdx.x] = red[0];
}

__global__ void k_scan2(int* bsum, int* offs) {
    if (threadIdx.x == 0) {
        int run = 0;
        for (int i = 0; i < NSCAN; i++) { int t = bsum[i]; bsum[i] = run; run += t; }
        offs[NN] = run;
    }
}

// scan3 + dis + cursor fused (removes the former k_dis_cursor launch)
__global__ __launch_bounds__(256) void k_scan3(const int* __restrict__ counts, const int* __restrict__ bsum,
                                               int* __restrict__ offs, float* __restrict__ dis,
                                               int* __restrict__ cursor) {
    __shared__ int ss[256];
    int tid = threadIdx.x;
    int base = blockIdx.x * 1024 + tid * 4;
    int v0 = counts[base], v1 = counts[base + 1], v2 = counts[base + 2], v3 = counts[base + 3];
    int ts = v0 + v1 + v2 + v3;
    ss[tid] = ts; __syncthreads();
    for (int o = 1; o < 256; o <<= 1) {
        int add = (tid >= o) ? ss[tid - o] : 0;
        __syncthreads();
        ss[tid] += add;
        __syncthreads();
    }
    int excl = ss[tid] - ts + bsum[blockIdx.x];
    int o0 = excl, o1 = excl + v0, o2 = o1 + v1, o3 = o2 + v2;
    offs[base] = o0; offs[base + 1] = o1; offs[base + 2] = o2; offs[base + 3] = o3;
    cursor[base] = o0; cursor[base + 1] = o1; cursor[base + 2] = o2; cursor[base + 3] = o3;
    dis[base]     = rsqrtf((float)v0 + 1.0f);
    dis[base + 1] = rsqrtf((float)v1 + 1.0f);
    dis[base + 2] = rsqrtf((float)v2 + 1.0f);
    dis[base + 3] = rsqrtf((float)v3 + 1.0f);
}

// scatter edges into CSR; also accumulate wsa[d] = sum_e dis[src] (for the agg-commute fold)
__global__ __launch_bounds__(256) void k_scatter(const int* __restrict__ ei, int* __restrict__ cursor,
                                                 int* __restrict__ srcs, float* __restrict__ sd,
                                                 const float* __restrict__ dis, float* __restrict__ wsa) {
    int e = blockIdx.x * 256 + threadIdx.x;
    int d = ei[NE + e], s = ei[e];
    int p = atomicAdd(&cursor[d], 1);
    float w = dis[s];
    srcs[p] = s;
    sd[p] = w;
    atomicAdd(&wsa[d], w);
}

// transpose + split fp32 W[K,F] -> bf16 Wh/Wl [F,K] (no affine; layer 1)
__global__ __launch_bounds__(256) void k_tsplit(const float* __restrict__ Wsrc,
                                                u16* __restrict__ Wh, u16* __restrict__ Wl,
                                                int K, int F) {
    int i = blockIdx.x * 256 + threadIdx.x;
    if (i < K * F) {
        int k = i / F, f = i % F;
        u16 h, l; splitbf(Wsrc[i], h, l);
        Wh[f * K + k] = h;
        Wl[f * K + k] = l;
    }
}

// BN-fold part 1 (stats inline): Wh/Wl[f,k] = split(sc[k]*W[k,f])
__global__ __launch_bounds__(256) void k_wsplit(const float* __restrict__ W,
                                                const float* __restrict__ S, const float* __restrict__ Q,
                                                const float* __restrict__ g, const float* __restrict__ b,
                                                u16* __restrict__ Wh, u16* __restrict__ Wl,
                                                int K, int F) {
    int i = blockIdx.x * 256 + threadIdx.x;
    if (i < K * F) {
        int k = i / F, f = i % F;
        float sc, sh; bnparams(S, Q, g, b, k, sc, sh);
        u16 h, l; splitbf(sc * W[i], h, l);
        Wh[f * K + k] = h;
        Wl[f * K + k] = l;
    }
}

// BN-fold part 2 (stats inline): c2[f] = sum_k sh[k]*W[k,f] — one wave per column
__global__ __launch_bounds__(256) void k_wc2(const float* __restrict__ W,
                                             const float* __restrict__ S, const float* __restrict__ Q,
                                             const float* __restrict__ g, const float* __restrict__ b,
                                             float* __restrict__ c2, int K, int F) {
    int wv = (blockIdx.x * 256 + threadIdx.x) >> 6;
    int lane = threadIdx.x & 63;
    if (wv >= F) return;
    float acc = 0.f;
    for (int k = lane; k < K; k += 64) {
        float sc, sh; bnparams(S, Q, g, b, k, sc, sh);
        acc += sh * W[k * F + wv];
    }
#pragma unroll
    for (int o = 1; o < 64; o <<= 1) acc += __shfl_xor(acc, o);
    if (lane == 0) c2[wv] = acc;
}

// ---------------- split MFMA GEMM: C = A @ W' (+epilogues), fp32-grade via bf16x3 ----------------
// AFP32: A is fp32 (layer 1, split at stage). Else A is two exact bf16 planes Ahi/Alo [N][K].
// W pre-split (+BN-folded) bf16 hi/lo [Fout][K]. C2: init acc with per-column constant. C fp16.
// TEPI (layer-2 agg-commute epilogue): v = acc + wsum[row]*c2[col] + bias[col]; t = relu(v);
//   write exact bf16 hi/lo planes Thi/Tlo and accumulate per-column BN stats into Sg/Qg.
template<int BM, int BN, int WCOLS, bool AFP32, bool C2, bool TEPI>
__global__ __launch_bounds__(256) void k_gemm(
    const float* __restrict__ Af, const u16* __restrict__ Ahi, const u16* __restrict__ Alo,
    const u16* __restrict__ Wh, const u16* __restrict__ Wl,
    _Float16* __restrict__ C, const int K, const int Fout, const float* __restrict__ c2,
    const float* __restrict__ bias, const float* __restrict__ wsa, const float* __restrict__ disv,
    u16* __restrict__ Thi, u16* __restrict__ Tlo, float* __restrict__ Sg, float* __restrict__ Qg)
{
    constexpr int AST = 40;                // 32 + 8 pad
    __shared__ u16 Ah[BM][AST], Al[BM][AST];
    __shared__ u16 Bh[BN][AST], Bl[BN][AST];
    __shared__ float redS[TEPI ? BN : 1], redQ[TEPI ? BN : 1];

    const int tid = threadIdx.x;
    const int row0 = blockIdx.y * BM;
    const int col0 = blockIdx.x * BN;

    const int wave = tid >> 6, lane = tid & 63;
    const int mb = (wave / WCOLS) * 64;
    const int nb = (wave % WCOLS) * 64;
    const int lm = lane & 15;
    const int lk = (lane >> 4) * 8;
    const int cb = col0 + nb + lm;

    if constexpr (TEPI) {
        for (int i = tid; i < BN; i += 256) { redS[i] = 0.f; redQ[i] = 0.f; }
    }

    float c2v[4] = {0.f, 0.f, 0.f, 0.f};
    if constexpr (C2) {
#pragma unroll
        for (int ni = 0; ni < 4; ni++) c2v[ni] = c2[cb + ni * 16];
    }

    f32x4 acc[4][4];
#pragma unroll
    for (int i = 0; i < 4; i++)
#pragma unroll
        for (int j = 0; j < 4; j++)
#pragma unroll
            for (int r = 0; r < 4; r++) acc[i][j][r] = c2v[j];

    const int stg_r = tid >> 3;        // 0..31
    const int stg_c = (tid & 7) * 4;   // 0,4..28

    for (int k0 = 0; k0 < K; k0 += 32) {
        __syncthreads();
#pragma unroll
        for (int p = 0; p < BM / 32; p++) {
            const int r = p * 32 + stg_r;
            if constexpr (AFP32) {
                const float4 v = *(const float4*)(Af + (size_t)(row0 + r) * K + k0 + stg_c);
                float y[4] = {v.x, v.y, v.z, v.w};
                ushort4 hv, lv;
#pragma unroll
                for (int q = 0; q < 4; q++) splitbf(y[q], ((u16*)&hv)[q], ((u16*)&lv)[q]);
                *(ushort4*)&Ah[r][stg_c] = hv;
                *(ushort4*)&Al[r][stg_c] = lv;
            } else {
                *(ushort4*)&Ah[r][stg_c] = *(const ushort4*)(Ahi + (size_t)(row0 + r) * K + k0 + stg_c);
                *(ushort4*)&Al[r][stg_c] = *(const ushort4*)(Alo + (size_t)(row0 + r) * K + k0 + stg_c);
            }
        }
#pragma unroll
        for (int p = 0; p < BN / 32; p++) {
            const int n = p * 32 + stg_r;
            *(ushort4*)&Bh[n][stg_c] = *(const ushort4*)(Wh + (size_t)(col0 + n) * K + k0 + stg_c);
            *(ushort4*)&Bl[n][stg_c] = *(const ushort4*)(Wl + (size_t)(col0 + n) * K + k0 + stg_c);
        }
        __syncthreads();

        bf16x8 ah[4], al[4], bh[4], bl[4];
#pragma unroll
        for (int mi = 0; mi < 4; mi++) {
            ah[mi] = *(const bf16x8*)&Ah[mb + mi * 16 + lm][lk];
            al[mi] = *(const bf16x8*)&Al[mb + mi * 16 + lm][lk];
        }
#pragma unroll
        for (int ni = 0; ni < 4; ni++) {
            bh[ni] = *(const bf16x8*)&Bh[nb + ni * 16 + lm][lk];
            bl[ni] = *(const bf16x8*)&Bl[nb + ni * 16 + lm][lk];
        }
#pragma unroll
        for (int mi = 0; mi < 4; mi++)
#pragma unroll
            for (int ni = 0; ni < 4; ni++) {
                acc[mi][ni] = __builtin_amdgcn_mfma_f32_16x16x32_bf16(al[mi], bh[ni], acc[mi][ni], 0, 0, 0);
                acc[mi][ni] = __builtin_amdgcn_mfma_f32_16x16x32_bf16(ah[mi], bl[ni], acc[mi][ni], 0, 0, 0);
                acc[mi][ni] = __builtin_amdgcn_mfma_f32_16x16x32_bf16(ah[mi], bh[ni], acc[mi][ni], 0, 0, 0);
            }
    }

    const int rb = row0 + mb + (lane >> 4) * 4;
    if constexpr (TEPI) {
        float c2l[4], bl4[4];
#pragma unroll
        for (int ni = 0; ni < 4; ni++) { c2l[ni] = c2[cb + ni * 16]; bl4[ni] = bias[cb + ni * 16]; }
        float ws[4][4];
#pragma unroll
        for (int mi = 0; mi < 4; mi++)
#pragma unroll
            for (int r = 0; r < 4; r++) {
                const int row = rb + mi * 16 + r;
                const float d = disv[row];
                ws[mi][r] = d * wsa[row] + d * d;
            }
#pragma unroll
        for (int ni = 0; ni < 4; ni++) {
            float s = 0.f, q = 0.f;
#pragma unroll
            for (int mi = 0; mi < 4; mi++)
#pragma unroll
                for (int r = 0; r < 4; r++) {
                    float v = acc[mi][ni][r] + ws[mi][r] * c2l[ni] + bl4[ni];
                    v = fmaxf(v, 0.f);
                    s += v; q += v * v;
                    u16 hh, ll; splitbf(v, hh, ll);
                    const size_t idx = (size_t)(rb + mi * 16 + r) * Fout + cb + ni * 16;
                    Thi[idx] = hh;
                    Tlo[idx] = ll;
                }
            atomicAdd(&redS[nb + ni * 16 + lm], s);
            atomicAdd(&redQ[nb + ni * 16 + lm], q);
        }
        __syncthreads();
        for (int i = tid; i < BN; i += 256) {
            atomicAdd(&Sg[col0 + i], redS[i]);
            atomicAdd(&Qg[col0 + i], redQ[i]);
        }
    } else {
#pragma unroll
        for (int mi = 0; mi < 4; mi++)
#pragma unroll
            for (int ni = 0; ni < 4; ni++)
#pragma unroll
                for (int r = 0; r < 4; r++)
                    C[(size_t)(rb + mi * 16 + r) * Fout + cb + ni * 16] = (_Float16)acc[mi][ni][r];
    }
}

// ---------------- aggregation: t = relu(dn*sum(sd_e*h_s) + dn^2*h_n + b), fused BN stats --------
// ONE NODE PER LANE-GROUP (LPG lanes), serial edge loop, EDGE-UNROLL x2 for 2 gathers in flight.
// h fp16 [N][CH]. FP16OUT: write t as fp16 single plane. Else exact bf16 hi/lo planes.
// BN stats held per-lane; merged across groups ONCE per wave at the end.
template<int CH, bool FP16OUT>
__global__ __launch_bounds__(256) void k_agg(
    const _Float16* __restrict__ h, u16* __restrict__ thi, u16* __restrict__ tlo,
    const float* __restrict__ bias,
    const int* __restrict__ off, const int* __restrict__ srcs, const float* __restrict__ sd,
    const float* __restrict__ dis, float* __restrict__ statS, float* __restrict__ statQ,
    _Float16* __restrict__ tf)
{
    constexpr int ECH = 16;            // channels per lane (32B fp16)
    constexpr int LPG = CH / ECH;      // lanes per node
    constexpr int G   = 64 / LPG;      // nodes per wave
    constexpr int NB  = NN / G;        // node batches
    __shared__ float redS[CH], redQ[CH];
    const int tid = threadIdx.x;
    for (int i = tid; i < CH; i += 256) { redS[i] = 0.f; redQ[i] = 0.f; }
    __syncthreads();

    const int lane = tid & 63;
    const int g = lane / LPG;          // node slot within wave
    const int c = (lane % LPG) * ECH;  // channel offset
    const int wid = (blockIdx.x * 256 + tid) >> 6;
    const int nw = (gridDim.x * 256) >> 6;

    float bs[ECH], bq[ECH], bv[ECH];
#pragma unroll
    for (int v = 0; v < ECH; v++) { bs[v] = 0.f; bq[v] = 0.f; bv[v] = bias[c + v]; }

    for (int b = wid; b < NB; b += nw) {
        const int n = b * G + g;
        const int p0 = off[n], p1 = off[n + 1];
        float a[ECH];
#pragma unroll
        for (int v = 0; v < ECH; v++) a[v] = 0.f;

        int p = p0;
        while (p + 2 <= p1) {          // two independent row-gathers in flight
            const int sA = srcs[p], sB = srcs[p + 1];
            const float wA = sd[p], wB = sd[p + 1];
            const _Float16* hA = h + (size_t)sA * CH + c;
            const _Float16* hB = h + (size_t)sB * CH + c;
            h8t a0 = *(const h8t*)hA;
            h8t a1 = *(const h8t*)(hA + 8);
            h8t b0 = *(const h8t*)hB;
            h8t b1 = *(const h8t*)(hB + 8);
#pragma unroll
            for (int v = 0; v < 8; v++) {
                a[v]     += wA * (float)a0[v] + wB * (float)b0[v];
                a[v + 8] += wA * (float)a1[v] + wB * (float)b1[v];
            }
            p += 2;
        }
        if (p < p1) {                  // odd tail
            const int sA = srcs[p];
            const float wA = sd[p];
            const _Float16* hA = h + (size_t)sA * CH + c;
            h8t a0 = *(const h8t*)hA;
            h8t a1 = *(const h8t*)(hA + 8);
#pragma unroll
            for (int v = 0; v < 8; v++) { a[v] += wA * (float)a0[v]; a[v + 8] += wA * (float)a1[v]; }
        }
        // no cross-lane merge needed: this lane owns channels c..c+15 of node n
        const float dn = dis[n];
        const float dn2 = dn * dn;
        const _Float16* hr = h + (size_t)n * CH + c;
        h8t hn0 = *(const h8t*)hr;
        h8t hn1 = *(const h8t*)(hr + 8);
        float o16[ECH];
#pragma unroll
        for (int v = 0; v < 8; v++) {
            o16[v] = fmaxf(dn * a[v] + dn2 * (float)hn0[v] + bv[v], 0.f);
            o16[v + 8] = fmaxf(dn * a[v + 8] + dn2 * (float)hn1[v] + bv[v + 8], 0.f);
        }
#pragma unroll
        for (int v = 0; v < ECH; v++) { bs[v] += o16[v]; bq[v] += o16[v] * o16[v]; }
        if constexpr (FP16OUT) {
            h8t o0, o1;
#pragma unroll
            for (int v = 0; v < 8; v++) { o0[v] = (_Float16)o16[v]; o1[v] = (_Float16)o16[v + 8]; }
            _Float16* tr = tf + (size_t)n * CH + c;
            *(h8t*)tr = o0; *(h8t*)(tr + 8) = o1;
        } else {
            u16x8 hv0, lv0, hv1, lv1;
#pragma unroll
            for (int v = 0; v < 8; v++) {
                splitbf(o16[v], ((u16*)&hv0)[v], ((u16*)&lv0)[v]);
                splitbf(o16[v + 8], ((u16*)&hv1)[v], ((u16*)&lv1)[v]);
            }
            u16* th = thi + (size_t)n * CH + c;
            u16* tl = tlo + (size_t)n * CH + c;
            *(u16x8*)th = hv0; *(u16x8*)(th + 8) = hv1;
            *(u16x8*)tl = lv0; *(u16x8*)(tl + 8) = lv1;
        }
    }
    // one-time stats merge across the G node-slots of this wave
#pragma unroll
    for (int o = LPG; o < 64; o <<= 1) {
#pragma unroll
        for (int v = 0; v < ECH; v++) { bs[v] += __shfl_xor(bs[v], o); bq[v] += __shfl_xor(bq[v], o); }
    }
    if (g == 0) {
#pragma unroll
        for (int v = 0; v < ECH; v++) { atomicAdd(&redS[c + v], bs[v]); atomicAdd(&redQ[c + v], bq[v]); }
    }
    __syncthreads();
    for (int i = tid; i < CH; i += 256) { atomicAdd(&statS[i], redS[i]); atomicAdd(&statQ[i], redQ[i]); }
}

// ---------------- pure linear aggregation: u = dn*sum(sd_e*t_s) + dn^2*t_n ----------------
// Same node-per-lane-group structure, edge-unroll x2. t fp16 [N][CH]; u -> exact bf16 hi/lo planes.
template<int CH>
__global__ __launch_bounds__(256) void k_agglin(
    const _Float16* __restrict__ t, u16* __restrict__ uhi, u16* __restrict__ ulo,
    const int* __restrict__ off, const int* __restrict__ srcs, const float* __restrict__ sd,
    const float* __restrict__ dis)
{
    constexpr int ECH = 16;
    constexpr int LPG = CH / ECH;
    constexpr int G   = 64 / LPG;
    constexpr int NB  = NN / G;
    const int tid = threadIdx.x;
    const int lane = tid & 63;
    const int g = lane / LPG;
    const int c = (lane % LPG) * ECH;
    const int wid = (blockIdx.x * 256 + tid) >> 6;
    const int nw = (gridDim.x * 256) >> 6;

    for (int b = wid; b < NB; b += nw) {
        const int n = b * G + g;
        const int p0 = off[n], p1 = off[n + 1];
        float a[ECH];
#pragma unroll
        for (int v = 0; v < ECH; v++) a[v] = 0.f;

        int p = p0;
        while (p + 2 <= p1) {
            const int sA = srcs[p], sB = srcs[p + 1];
            const float wA = sd[p], wB = sd[p + 1];
            const _Float16* hA = t + (size_t)sA * CH + c;
            const _Float16* hB = t + (size_t)sB * CH + c;
            h8t a0 = *(const h8t*)hA;
            h8t a1 = *(const h8t*)(hA + 8);
            h8t b0 = *(const h8t*)hB;
            h8t b1 = *(const h8t*)(hB + 8);
#pragma unroll
            for (int v = 0; v < 8; v++) {
                a[v]     += wA * (float)a0[v] + wB * (float)b0[v];
                a[v + 8] += wA * (float)a1[v] + wB * (float)b1[v];
            }
            p += 2;
        }
        if (p < p1) {
            const int sA = srcs[p];
            const float wA = sd[p];
            const _Float16* hA = t + (size_t)sA * CH + c;
            h8t a0 = *(const h8t*)hA;
            h8t a1 = *(const h8t*)(hA + 8);
#pragma unroll
            for (int v = 0; v < 8; v++) { a[v] += wA * (float)a0[v]; a[v + 8] += wA * (float)a1[v]; }
        }
        const float dn = dis[n];
        const float dn2 = dn * dn;
        const _Float16* hr = t + (size_t)n * CH + c;
        h8t hn0 = *(const h8t*)hr;
        h8t hn1 = *(const h8t*)(hr + 8);
        u16x8 hv0, lv0, hv1, lv1;
#pragma unroll
        for (int v = 0; v < 8; v++) {
            float o0 = dn * a[v] + dn2 * (float)hn0[v];
            float o1 = dn * a[v + 8] + dn2 * (float)hn1[v];
            splitbf(o0, ((u16*)&hv0)[v], ((u16*)&lv0)[v]);
            splitbf(o1, ((u16*)&hv1)[v], ((u16*)&lv1)[v]);
        }
        u16* th = uhi + (size_t)n * CH + c;
        u16* tl = ulo + (size_t)n * CH + c;
        *(u16x8*)th = hv0; *(u16x8*)(th + 8) = hv1;
        *(u16x8*)tl = lv0; *(u16x8*)(tl + 8) = lv1;
    }
}

// ---------------- small dense layer: C[N,F] = affine(A)[N,K] @ W[K,F] (+bias) ----------------
// A = bf16 hi/lo planes, C fp16, fp32 compute. BN params computed inline from raw stats.
// STATS: fused per-column sum/sumsq of acc.
template<int K, int F, bool BIAS, bool STATS>
__global__ __launch_bounds__(256) void k_smm(
    const u16* __restrict__ Ahi, const u16* __restrict__ Alo,
    const float* __restrict__ Wf, const float* __restrict__ bias,
    _Float16* __restrict__ C,
    const float* __restrict__ Sb, const float* __restrict__ Qb,
    const float* __restrict__ gb, const float* __restrict__ bb,
    float* __restrict__ Sg, float* __restrict__ Qg)
{
    __shared__ float Wl[K * F];
    __shared__ float scl[K], shl[K], bl[F];
    __shared__ float redS[F], redQ[F];
    const int tid = threadIdx.x;
    for (int i = tid; i < K * F; i += 256) Wl[i] = Wf[i];
    if (tid < K) {
        float s, h_; bnparams(Sb, Qb, gb, bb, tid, s, h_);
        scl[tid] = s; shl[tid] = h_;
    }
    if (tid < F) {
        bl[tid] = 0.f;
        if constexpr (BIAS) bl[tid] = bias[tid];
        if constexpr (STATS) { redS[tid] = 0.f; redQ[tid] = 0.f; }
    }
    __syncthreads();
    const int n = blockIdx.x * 256 + tid;
    float acc[F];
#pragma unroll
    for (int f = 0; f < F; f++) acc[f] = bl[f];
    const u16* ah = Ahi + (size_t)n * K;
    const u16* al = Alo + (size_t)n * K;
    for (int k = 0; k < K; k += 4) {
        ushort4 hv = *(const ushort4*)(ah + k);
        ushort4 lv = *(const ushort4*)(al + k);
        float y0 = (bf2f(hv.x) + bf2f(lv.x)) * scl[k] + shl[k];
        float y1 = (bf2f(hv.y) + bf2f(lv.y)) * scl[k + 1] + shl[k + 1];
        float y2 = (bf2f(hv.z) + bf2f(lv.z)) * scl[k + 2] + shl[k + 2];
        float y3 = (bf2f(hv.w) + bf2f(lv.w)) * scl[k + 3] + shl[k + 3];
#pragma unroll
        for (int f = 0; f < F; f += 4) {
            float4 w0 = *(const float4*)&Wl[k * F + f];
            float4 w1 = *(const float4*)&Wl[(k + 1) * F + f];
            float4 w2 = *(const float4*)&Wl[(k + 2) * F + f];
            float4 w3 = *(const float4*)&Wl[(k + 3) * F + f];
            acc[f + 0] += y0 * w0.x + y1 * w1.x + y2 * w2.x + y3 * w3.x;
            acc[f + 1] += y0 * w0.y + y1 * w1.y + y2 * w2.y + y3 * w3.y;
            acc[f + 2] += y0 * w0.z + y1 * w1.z + y2 * w2.z + y3 * w3.z;
            acc[f + 3] += y0 * w0.w + y1 * w1.w + y2 * w2.w + y3 * w3.w;
        }
    }
    _Float16* cr = C + (size_t)n * F;
#pragma unroll
    for (int f = 0; f < F; f++) cr[f] = (_Float16)acc[f];
    if constexpr (STATS) {
        float s[F], q[F];
#pragma unroll
        for (int f = 0; f < F; f++) { s[f] = acc[f]; q[f] = acc[f] * acc[f]; }
#pragma unroll
        for (int o = 1; o < 64; o <<= 1) {
#pragma unroll
            for (int f = 0; f < F; f++) { s[f] += __shfl_xor(s[f], o); q[f] += __shfl_xor(q[f], o); }
        }
        if ((tid & 63) == 0) {
#pragma unroll
            for (int f = 0; f < F; f++) { atomicAdd(&redS[f], s[f]); atomicAdd(&redQ[f], q[f]); }
        }
        __syncthreads();
        for (int i = tid; i < F; i += 256) { atomicAdd(&Sg[i], redS[i]); atomicAdd(&Qg[i], redQ[i]); }
    }
}

// ---------------- gate layer 2: g2 = relu(bn1(g1)) @ gW2 + gb2, stats inline + fused ----------------
__global__ __launch_bounds__(256) void k_gate2(const _Float16* __restrict__ g1,
                                               const float* __restrict__ S1g, const float* __restrict__ Q1g,
                                               const float* __restrict__ gg, const float* __restrict__ gbb,
                                               const float* __restrict__ w2, const float* __restrict__ b2,
                                               float* __restrict__ g2,
                                               float* __restrict__ Sg, float* __restrict__ Qg) {
    __shared__ float wl[16], scl[16], shl[16], b2l[1];
    __shared__ float redSg[1], redQg[1];
    const int tid = threadIdx.x;
    if (tid < 16) {
        wl[tid] = w2[tid];
        float s, h_; bnparams(S1g, Q1g, gg, gbb, tid, s, h_);
        scl[tid] = s; shl[tid] = h_;
    }
    if (tid == 0) { b2l[0] = b2[0]; redSg[0] = 0.f; redQg[0] = 0.f; }
    __syncthreads();
    const int n = blockIdx.x * 256 + tid;
    const _Float16* r = g1 + (size_t)n * 16;
    float acc = b2l[0];
#pragma unroll
    for (int k = 0; k < 16; k++) {
        float y = fmaxf((float)r[k] * scl[k] + shl[k], 0.f);
        acc += y * wl[k];
    }
    g2[n] = acc;
    float s = acc, q = acc * acc;
#pragma unroll
    for (int o = 1; o < 64; o <<= 1) { s += __shfl_xor(s, o); q += __shfl_xor(q, o); }
    if ((tid & 63) == 0) { atomicAdd(&redSg[0], s); atomicAdd(&redQg[0], q); }
    __syncthreads();
    if (tid == 0) { atomicAdd(&Sg[0], redSg[0]); atomicAdd(&Qg[0], redQg[0]); }
}

// ---------------- segment softmax + pooling + FC + softmax (BN params inline) ----------------
__global__ __launch_bounds__(256) void k_pool(const u16* __restrict__ t4hi, const u16* __restrict__ t4lo,
                                              const float* __restrict__ S4, const float* __restrict__ Q4,
                                              const float* __restrict__ g4, const float* __restrict__ b4,
                                              const float* __restrict__ g2,
                                              const float* __restrict__ gS2, const float* __restrict__ gQ2,
                                              const float* __restrict__ gg2, const float* __restrict__ gbb2,
                                              const float* __restrict__ fcW, const float* __restrict__ fcb,
                                              float* __restrict__ out) {
    __shared__ float fw[32 * NCLS], fbl[NCLS], sc4l[32], sh4l[32], g2p[2];
    const int tid = threadIdx.x;
    for (int i = tid; i < 32 * NCLS; i += 256) fw[i] = fcW[i];
    if (tid < NCLS) fbl[tid] = fcb[tid];
    if (tid < 32) {
        float s, h_; bnparams(S4, Q4, g4, b4, tid, s, h_);
        sc4l[tid] = s; sh4l[tid] = h_;
    }
    if (tid == 0) {
        float s, h_; bnparams(gS2, gQ2, gg2, gbb2, 0, s, h_);
        g2p[0] = s; g2p[1] = h_;
    }
    __syncthreads();
    const int b = blockIdx.x * 256 + tid;
    const float s2 = g2p[0], h2 = g2p[1];
    const int base = b * GSZ;

    float gv[GSZ];
    float m = -1e30f;
#pragma unroll
    for (int i = 0; i < GSZ; i++) {
        float v = fmaxf(g2[base + i] * s2 + h2, 0.f);
        gv[i] = v; m = fmaxf(m, v);
    }
    float ssum = 0.f;
#pragma unroll
    for (int i = 0; i < GSZ; i++) { float e = __expf(gv[i] - m); gv[i] = e; ssum += e; }
    const float inv = 1.0f / ssum;

    float pooled[32];
#pragma unroll
    for (int c = 0; c < 32; c++) pooled[c] = 0.f;
#pragma unroll
    for (int i = 0; i < GSZ; i++) {
        const float a = gv[i] * inv;
        const u16* th = t4hi + (size_t)(base + i) * 32;
        const u16* tl = t4lo + (size_t)(base + i) * 32;
#pragma unroll
        for (int c = 0; c < 32; c += 4) {
            ushort4 hv = *(const ushort4*)(th + c);
            ushort4 lv = *(const ushort4*)(tl + c);
            pooled[c + 0] += a * ((bf2f(hv.x) + bf2f(lv.x)) * sc4l[c + 0] + sh4l[c + 0]);
            pooled[c + 1] += a * ((bf2f(hv.y) + bf2f(lv.y)) * sc4l[c + 1] + sh4l[c + 1]);
            pooled[c + 2] += a * ((bf2f(hv.z) + bf2f(lv.z)) * sc4l[c + 2] + sh4l[c + 2]);
            pooled[c + 3] += a * ((bf2f(hv.w) + bf2f(lv.w)) * sc4l[c + 3] + sh4l[c + 3]);
        }
    }
    float lg[NCLS];
    float mx = -1e30f;
#pragma unroll
    for (int j = 0; j < NCLS; j++) {
        float a = fbl[j];
#pragma unroll
        for (int c = 0; c < 32; c++) a += pooled[c] * fw[c * NCLS + j];
        lg[j] = a; mx = fmaxf(mx, a);
    }
    float es = 0.f;
#pragma unroll
    for (int j = 0; j < NCLS; j++) { float e = __expf(lg[j] - mx); lg[j] = e; es += e; }
    const float iv = 1.0f / es;
#pragma unroll
    for (int j = 0; j < NCLS; j++) out[b * NCLS + j] = lg[j] * iv;
}

// ---------------- host ----------------
extern "C" void kernel_launch(void* const* d_in, const int* in_sizes, int n_in,
                              void* d_out, int out_size, void* d_ws, size_t ws_size,
                              hipStream_t stream) {
    (void)in_sizes; (void)n_in; (void)out_size; (void)ws_size;
    const float* x    = (const float*)d_in[0];
    const int*   ei   = (const int*)d_in[1];
    const float* W1   = (const float*)d_in[2];
    const float* b1   = (const float*)d_in[3];
    const float* bn1g = (const float*)d_in[4];
    const float* bn1b = (const float*)d_in[5];
    const float* W2   = (const float*)d_in[6];
    const float* b2   = (const float*)d_in[7];
    const float* bn2g = (const float*)d_in[8];
    const float* bn2b = (const float*)d_in[9];
    const float* W3   = (const float*)d_in[10];
    const float* b3   = (const float*)d_in[11];
    const float* bn3g = (const float*)d_in[12];
    const float* bn3b = (const float*)d_in[13];
    const float* W4   = (const float*)d_in[14];
    const float* b4   = (const float*)d_in[15];
    const float* bn4g = (const float*)d_in[16];
    const float* bn4b = (const float*)d_in[17];
    const float* gW1  = (const float*)d_in[18];
    const float* gb1  = (const float*)d_in[19];
    const float* gbn1g = (const float*)d_in[20];
    const float* gbn1b = (const float*)d_in[21];
    const float* gW2  = (const float*)d_in[22];
    const float* gb2  = (const float*)d_in[23];
    const float* gbn2g = (const float*)d_in[24];
    const float* gbn2b = (const float*)d_in[25];
    const float* fcW  = (const float*)d_in[26];
    const float* fcb  = (const float*)d_in[27];
    float* out = (float*)d_out;

    char* base = (char*)d_ws;
    size_t off_ = 0;
    auto carve = [&](size_t bytes) -> char* {
        char* p = base + off_;
        off_ = (off_ + bytes + 255) & ~(size_t)255;
        return p;
    };
    int*   counts = (int*)carve((size_t)NN * 4);
    float* stats  = (float*)carve(994 * 4);
    float* wsa    = (float*)carve((size_t)NN * 4);
    const size_t zero_bytes = off_;
    int*   offs   = (int*)carve((size_t)(NN + 1) * 4);
    int*   cursor = (int*)carve((size_t)NN * 4);
    int*   srcs   = (int*)carve((size_t)NE * 4);
    float* sd     = (float*)carve((size_t)NE * 4);
    float* dis    = (float*)carve((size_t)NN * 4);
    int*   bsum   = (int*)carve(NSCAN * 4);
    u16*   Wt1h   = (u16*)carve(512 * 128 * 2);
    u16*   Wt1l   = (u16*)carve(512 * 128 * 2);
    u16*   Wt2h   = (u16*)carve(128 * 256 * 2);
    u16*   Wt2l   = (u16*)carve(128 * 256 * 2);
    u16*   Wt3h   = (u16*)carve(256 * 64 * 2);
    u16*   Wt3l   = (u16*)carve(256 * 64 * 2);
    float* c2_2   = (float*)carve(256 * 4);
    float* c2_3   = (float*)carve(64 * 4);
    float* g2raw  = (float*)carve((size_t)NN * 4);
    _Float16* P   = (_Float16*)carve((size_t)NN * 256 * 2);   // h buffer (fp16, up to 256 ch)
    u16*   Qhi    = (u16*)carve((size_t)NN * 128 * 2);        // t/u planes (<=128 ch)
    u16*   Qlo    = (u16*)carve((size_t)NN * 128 * 2);
    u16*   Rhi    = (u16*)carve((size_t)NN * 256 * 2);        // t2 planes (256 ch)
    u16*   Rlo    = (u16*)carve((size_t)NN * 256 * 2);
    // t1 fp16 single plane lives in the upper half of P (h1 only uses [N,128])
    _Float16* T1f = P + (size_t)NN * 128;

    float* S1 = stats;      float* Q1s = S1 + 128;
    float* S2 = Q1s + 128;  float* Q2s = S2 + 256;
    float* S3 = Q2s + 256;  float* Q3s = S3 + 64;
    float* S4 = Q3s + 64;   float* Q4s = S4 + 32;
    float* gS1 = Q4s + 32;  float* gQ1 = gS1 + 16;
    float* gS2 = gQ1 + 16;  float* gQ2 = gS2 + 1;

    hipMemsetAsync(d_ws, 0, zero_bytes, stream);

    k_hist<<<NE / 256, 256, 0, stream>>>(ei, counts);
    k_scan1<<<NSCAN, 256, 0, stream>>>(counts, bsum);
    k_scan2<<<1, 64, 0, stream>>>(bsum, offs);
    k_scan3<<<NSCAN, 256, 0, stream>>>(counts, bsum, offs, dis, cursor);
    k_scatter<<<NE / 256, 256, 0, stream>>>(ei, cursor, srcs, sd, dis, wsa);
    k_tsplit<<<(512 * 128 + 255) / 256, 256, 0, stream>>>(W1, Wt1h, Wt1l, 512, 128);

    // layer 1: h1 = x @ W1 -> P (N x 128 fp16); t1 = relu(agg(h1)+b1) -> T1f fp16 + BN1 stats
    k_gemm<128, 128, 2, true, false, false><<<dim3(1, NN / 128), 256, 0, stream>>>(
        x, nullptr, nullptr, Wt1h, Wt1l, P, 512, 128, nullptr,
        nullptr, nullptr, nullptr, nullptr, nullptr, nullptr, nullptr);
    k_agg<128, true><<<1792, 256, 0, stream>>>(P, nullptr, nullptr, b1, offs, srcs, sd, dis, S1, Q1s, T1f);

    // layer 2, agg-commute: u = agg(t1) on 128 ch -> Q planes; then
    // t2 = relu(u@(sc1*W2) + wsum*(sh1@W2) + b2) in the GEMM epilogue -> R planes + BN2 stats
    k_agglin<128><<<1792, 256, 0, stream>>>(T1f, Qhi, Qlo, offs, srcs, sd, dis);
    k_wsplit<<<(128 * 256 + 255) / 256, 256, 0, stream>>>(W2, S1, Q1s, bn1g, bn1b, Wt2h, Wt2l, 128, 256);
    k_wc2<<<(256 * 64 + 255) / 256, 256, 0, stream>>>(W2, S1, Q1s, bn1g, bn1b, c2_2, 128, 256);
    k_gemm<128, 128, 2, false, false, true><<<dim3(2, NN / 128), 256, 0, stream>>>(
        nullptr, Qhi, Qlo, Wt2h, Wt2l, nullptr, 128, 256, c2_2,
        b2, wsa, dis, Rhi, Rlo, S2, Q2s);

    // layer 3 (BN folded into W3): h3 = t2 @ W3' + c2 -> P (N x 64); t3 -> Q planes
    k_wsplit<<<(256 * 64 + 255) / 256, 256, 0, stream>>>(W3, S2, Q2s, bn2g, bn2b, Wt3h, Wt3l, 256, 64);
    k_wc2<<<(64 * 64 + 255) / 256, 256, 0, stream>>>(W3, S2, Q2s, bn2g, bn2b, c2_3, 256, 64);
    k_gemm<256, 64, 1, false, true, false><<<dim3(1, NN / 256), 256, 0, stream>>>(
        nullptr, Rhi, Rlo, Wt3h, Wt3l, P, 256, 64, c2_3,
        nullptr, nullptr, nullptr, nullptr, nullptr, nullptr, nullptr);
    k_agg<64, false><<<1792, 256, 0, stream>>>(P, Qhi, Qlo, b3, offs, srcs, sd, dis, S3, Q3s, nullptr);

    // layer 4: h4 = bn3(t3) @ W4 -> P (N x 32 fp16); t4 -> Q planes (32 ch)
    k_smm<64, 32, false, false><<<NN / 256, 256, 0, stream>>>(Qhi, Qlo, W4, nullptr, P,
                                                              S3, Q3s, bn3g, bn3b, nullptr, nullptr);
    k_agg<32, false><<<896, 256, 0, stream>>>(P, Qhi, Qlo, b4, offs, srcs, sd, dis, S4, Q4s, nullptr);

    // gate 1: g1 = bn4(t4) @ gW1 + gb1 -> P (N x 16 fp16), stats fused
    k_smm<32, 16, true, true><<<NN / 256, 256, 0, stream>>>(Qhi, Qlo, gW1, gb1, P,
                                                            S4, Q4s, bn4g, bn4b, gS1, gQ1);

    // gate 2: g2 = relu(gbn1(g1)) @ gW2 + gb2 -> g2raw (N, fp32), stats fused
    k_gate2<<<NN / 256, 256, 0, stream>>>(P, gS1, gQ1, gbn1g, gbn1b, gW2, gb2, g2raw, gS2, gQ2);

    // pooling + FC + softmax (BN4 + gate-BN2 params computed inline)
    k_pool<<<NBATCH / 256, 256, 0, stream>>>(Qhi, Qlo, S4, Q4s, bn4g, bn4b,
                                             g2raw, gS2, gQ2, gbn2g, gbn2b, fcW, fcb, out);
}

// Round 7
// 952.652 us; speedup vs baseline: 1.2015x; 1.0042x over previous
//
#include <hip/hip_runtime.h>

#define NN 114688      // nodes
#define NE 917504      // edges
#define NBATCH 8192    // graphs
#define GSZ 14         // nodes per graph
#define NCLS 10
#define EPSB 1e-5f
#define NSCAN 112      // NN / 1024

typedef unsigned short u16;
typedef short bf16x8 __attribute__((ext_vector_type(8)));
typedef float f32x4 __attribute__((ext_vector_type(4)));
typedef _Float16 h8t __attribute__((ext_vector_type(8)));
typedef unsigned short u16x8 __attribute__((ext_vector_type(8)));

__device__ __forceinline__ float bf2f(u16 u) {
    union { unsigned int i; float f; } v; v.i = ((unsigned int)u) << 16; return v.f;
}
__device__ __forceinline__ u16 f2bf(float f) {
    union { float f; unsigned int i; } v; v.f = f;
    unsigned int i = v.i;
    unsigned int r = i + 0x7FFFu + ((i >> 16) & 1u);   // RNE
    return (u16)(r >> 16);
}
__device__ __forceinline__ void splitbf(float y, u16& h, u16& l) {
    h = f2bf(y);
    l = f2bf(y - bf2f(h));
}
// BN scale/shift from raw stats — folded into every consumer (replaces k_bnpar launches)
__device__ __forceinline__ void bnparams(const float* __restrict__ S, const float* __restrict__ Q,
                                         const float* __restrict__ g, const float* __restrict__ b,
                                         int c, float& sc, float& sh) {
    const float invn = 1.0f / (float)NN;
    float mean = S[c] * invn;
    float var = Q[c] * invn - mean * mean;
    float s = g[c] * rsqrtf(fmaxf(var, 0.f) + EPSB);
    sc = s;
    sh = b[c] - mean * s;
}

// ---------------- graph preprocessing ----------------
__global__ __launch_bounds__(256) void k_hist(const int* __restrict__ ei, int* __restrict__ counts) {
    int e = blockIdx.x * 256 + threadIdx.x;
    atomicAdd(&counts[ei[NE + e]], 1);
}

__global__ __launch_bounds__(256) void k_scan1(const int* __restrict__ counts, int* __restrict__ bsum) {
    __shared__ int red[256];
    int tid = threadIdx.x;
    int base = blockIdx.x * 1024 + tid * 4;
    int s = counts[base] + counts[base + 1] + counts[base + 2] + counts[base + 3];
    red[tid] = s; __syncthreads();
    for (int o = 128; o > 0; o >>= 1) {
        if (tid < o) red[tid] += red[tid + o];
        __syncthreads();
    }
    if (tid == 0) bsum[blockIdx.x] = red[0];
}

// parallel 112-element exclusive scan (was a single-threaded serial loop ~15-25 us)
__global__ __launch_bounds__(128) void k_scan2(int* __restrict__ bsum, int* __restrict__ offs) {
    __shared__ int ss[128];
    int tid = threadIdx.x;
    int v = (tid < NSCAN) ? bsum[tid] : 0;
    ss[tid] = v; __syncthreads();
    for (int o = 1; o < 128; o <<= 1) {
        int add = (tid >= o) ? ss[tid - o] : 0;
        __syncthreads();
        ss[tid] += add;
        __syncthreads();
    }
    if (tid < NSCAN) bsum[tid] = ss[tid] - v;     // exclusive
    if (tid == NSCAN - 1) offs[NN] = ss[tid];     // total
}

// scan3 + dis + cursor fused
__global__ __launch_bounds__(256) void k_scan3(const int* __restrict__ counts, const int* __restrict__ bsum,
                                               int* __restrict__ offs, float* __restrict__ dis,
                                               int* __restrict__ cursor) {
    __shared__ int ss[256];
    int tid = threadIdx.x;
    int base = blockIdx.x * 1024 + tid * 4;
    int v0 = counts[base], v1 = counts[base + 1], v2 = counts[base + 2], v3 = counts[base + 3];
    int ts = v0 + v1 + v2 + v3;
    ss[tid] = ts; __syncthreads();
    for (int o = 1; o < 256; o <<= 1) {
        int add = (tid >= o) ? ss[tid - o] : 0;
        __syncthreads();
        ss[tid] += add;
        __syncthreads();
    }
    int excl = ss[tid] - ts + bsum[blockIdx.x];
    int o0 = excl, o1 = excl + v0, o2 = o1 + v1, o3 = o2 + v2;
    offs[base] = o0; offs[base + 1] = o1; offs[base + 2] = o2; offs[base + 3] = o3;
    cursor[base] = o0; cursor[base + 1] = o1; cursor[base + 2] = o2; cursor[base + 3] = o3;
    dis[base]     = rsqrtf((float)v0 + 1.0f);
    dis[base + 1] = rsqrtf((float)v1 + 1.0f);
    dis[base + 2] = rsqrtf((float)v2 + 1.0f);
    dis[base + 3] = rsqrtf((float)v3 + 1.0f);
}

// scatter edges into CSR as packed 8B records {src, weight}; accumulate wsa[d] = sum_e dis[src]
__global__ __launch_bounds__(256) void k_scatter(const int* __restrict__ ei, int* __restrict__ cursor,
                                                 int2* __restrict__ es,
                                                 const float* __restrict__ dis, float* __restrict__ wsa) {
    int e = blockIdx.x * 256 + threadIdx.x;
    int d = ei[NE + e], s = ei[e];
    int p = atomicAdd(&cursor[d], 1);
    float w = dis[s];
    es[p] = make_int2(s, __float_as_int(w));
    atomicAdd(&wsa[d], w);
}

// transpose + split fp32 W[K,F] -> bf16 Wh/Wl [F,K] (no affine; layer 1)
__global__ __launch_bounds__(256) void k_tsplit(const float* __restrict__ Wsrc,
                                                u16* __restrict__ Wh, u16* __restrict__ Wl,
                                                int K, int F) {
    int i = blockIdx.x * 256 + threadIdx.x;
    if (i < K * F) {
        int k = i / F, f = i % F;
        u16 h, l; splitbf(Wsrc[i], h, l);
        Wh[f * K + k] = h;
        Wl[f * K + k] = l;
    }
}

// BN-fold (stats inline): Wh/Wl[f,k] = split(sc[k]*W[k,f]); c2[f] += sh[k]*W[k,f] (atomic fold,
// replaces the separate k_wc2 launch; c2 zeroed by the workspace memset)
__global__ __launch_bounds__(256) void k_wsplit(const float* __restrict__ W,
                                                const float* __restrict__ S, const float* __restrict__ Q,
                                                const float* __restrict__ g, const float* __restrict__ b,
                                                u16* __restrict__ Wh, u16* __restrict__ Wl,
                                                float* __restrict__ c2,
                                                int K, int F) {
    int i = blockIdx.x * 256 + threadIdx.x;
    if (i < K * F) {
        int k = i / F, f = i % F;
        float sc, sh; bnparams(S, Q, g, b, k, sc, sh);
        float w = W[i];
        u16 h, l; splitbf(sc * w, h, l);
        Wh[f * K + k] = h;
        Wl[f * K + k] = l;
        atomicAdd(&c2[f], sh * w);
    }
}

// ---------------- split MFMA GEMM: C = A @ W' (+epilogues), fp32-grade via bf16x3 ----------------
template<int BM, int BN, int WCOLS, bool AFP32, bool C2, bool TEPI>
__global__ __launch_bounds__(256) void k_gemm(
    const float* __restrict__ Af, const u16* __restrict__ Ahi, const u16* __restrict__ Alo,
    const u16* __restrict__ Wh, const u16* __restrict__ Wl,
    _Float16* __restrict__ C, const int K, const int Fout, const float* __restrict__ c2,
    const float* __restrict__ bias, const float* __restrict__ wsa, const float* __restrict__ disv,
    u16* __restrict__ Thi, u16* __restrict__ Tlo, float* __restrict__ Sg, float* __restrict__ Qg)
{
    constexpr int AST = 40;                // 32 + 8 pad
    __shared__ u16 Ah[BM][AST], Al[BM][AST];
    __shared__ u16 Bh[BN][AST], Bl[BN][AST];
    __shared__ float redS[TEPI ? BN : 1], redQ[TEPI ? BN : 1];

    const int tid = threadIdx.x;
    const int row0 = blockIdx.y * BM;
    const int col0 = blockIdx.x * BN;

    const int wave = tid >> 6, lane = tid & 63;
    const int mb = (wave / WCOLS) * 64;
    const int nb = (wave % WCOLS) * 64;
    const int lm = lane & 15;
    const int lk = (lane >> 4) * 8;
    const int cb = col0 + nb + lm;

    if constexpr (TEPI) {
        for (int i = tid; i < BN; i += 256) { redS[i] = 0.f; redQ[i] = 0.f; }
    }

    float c2v[4] = {0.f, 0.f, 0.f, 0.f};
    if constexpr (C2) {
#pragma unroll
        for (int ni = 0; ni < 4; ni++) c2v[ni] = c2[cb + ni * 16];
    }

    f32x4 acc[4][4];
#pragma unroll
    for (int i = 0; i < 4; i++)
#pragma unroll
        for (int j = 0; j < 4; j++)
#pragma unroll
            for (int r = 0; r < 4; r++) acc[i][j][r] = c2v[j];

    const int stg_r = tid >> 3;        // 0..31
    const int stg_c = (tid & 7) * 4;   // 0,4..28

    for (int k0 = 0; k0 < K; k0 += 32) {
        __syncthreads();
#pragma unroll
        for (int p = 0; p < BM / 32; p++) {
            const int r = p * 32 + stg_r;
            if constexpr (AFP32) {
                const float4 v = *(const float4*)(Af + (size_t)(row0 + r) * K + k0 + stg_c);
                float y[4] = {v.x, v.y, v.z, v.w};
                ushort4 hv, lv;
#pragma unroll
                for (int q = 0; q < 4; q++) splitbf(y[q], ((u16*)&hv)[q], ((u16*)&lv)[q]);
                *(ushort4*)&Ah[r][stg_c] = hv;
                *(ushort4*)&Al[r][stg_c] = lv;
            } else {
                *(ushort4*)&Ah[r][stg_c] = *(const ushort4*)(Ahi + (size_t)(row0 + r) * K + k0 + stg_c);
                *(ushort4*)&Al[r][stg_c] = *(const ushort4*)(Alo + (size_t)(row0 + r) * K + k0 + stg_c);
            }
        }
#pragma unroll
        for (int p = 0; p < BN / 32; p++) {
            const int n = p * 32 + stg_r;
            *(ushort4*)&Bh[n][stg_c] = *(const ushort4*)(Wh + (size_t)(col0 + n) * K + k0 + stg_c);
            *(ushort4*)&Bl[n][stg_c] = *(const ushort4*)(Wl + (size_t)(col0 + n) * K + k0 + stg_c);
        }
        __syncthreads();

        bf16x8 ah[4], al[4], bh[4], bl[4];
#pragma unroll
        for (int mi = 0; mi < 4; mi++) {
            ah[mi] = *(const bf16x8*)&Ah[mb + mi * 16 + lm][lk];
            al[mi] = *(const bf16x8*)&Al[mb + mi * 16 + lm][lk];
        }
#pragma unroll
        for (int ni = 0; ni < 4; ni++) {
            bh[ni] = *(const bf16x8*)&Bh[nb + ni * 16 + lm][lk];
            bl[ni] = *(const bf16x8*)&Bl[nb + ni * 16 + lm][lk];
        }
#pragma unroll
        for (int mi = 0; mi < 4; mi++)
#pragma unroll
            for (int ni = 0; ni < 4; ni++) {
                acc[mi][ni] = __builtin_amdgcn_mfma_f32_16x16x32_bf16(al[mi], bh[ni], acc[mi][ni], 0, 0, 0);
                acc[mi][ni] = __builtin_amdgcn_mfma_f32_16x16x32_bf16(ah[mi], bl[ni], acc[mi][ni], 0, 0, 0);
                acc[mi][ni] = __builtin_amdgcn_mfma_f32_16x16x32_bf16(ah[mi], bh[ni], acc[mi][ni], 0, 0, 0);
            }
    }

    const int rb = row0 + mb + (lane >> 4) * 4;
    if constexpr (TEPI) {
        float c2l[4], bl4[4];
#pragma unroll
        for (int ni = 0; ni < 4; ni++) { c2l[ni] = c2[cb + ni * 16]; bl4[ni] = bias[cb + ni * 16]; }
        float ws[4][4];
#pragma unroll
        for (int mi = 0; mi < 4; mi++)
#pragma unroll
            for (int r = 0; r < 4; r++) {
                const int row = rb + mi * 16 + r;
                const float d = disv[row];
                ws[mi][r] = d * wsa[row] + d * d;
            }
#pragma unroll
        for (int ni = 0; ni < 4; ni++) {
            float s = 0.f, q = 0.f;
#pragma unroll
            for (int mi = 0; mi < 4; mi++)
#pragma unroll
                for (int r = 0; r < 4; r++) {
                    float v = acc[mi][ni][r] + ws[mi][r] * c2l[ni] + bl4[ni];
                    v = fmaxf(v, 0.f);
                    s += v; q += v * v;
                    u16 hh, ll; splitbf(v, hh, ll);
                    const size_t idx = (size_t)(rb + mi * 16 + r) * Fout + cb + ni * 16;
                    Thi[idx] = hh;
                    Tlo[idx] = ll;
                }
            atomicAdd(&redS[nb + ni * 16 + lm], s);
            atomicAdd(&redQ[nb + ni * 16 + lm], q);
        }
        __syncthreads();
        for (int i = tid; i < BN; i += 256) {
            atomicAdd(&Sg[col0 + i], redS[i]);
            atomicAdd(&Qg[col0 + i], redQ[i]);
        }
    } else {
#pragma unroll
        for (int mi = 0; mi < 4; mi++)
#pragma unroll
            for (int ni = 0; ni < 4; ni++)
#pragma unroll
                for (int r = 0; r < 4; r++)
                    C[(size_t)(rb + mi * 16 + r) * Fout + cb + ni * 16] = (_Float16)acc[mi][ni][r];
    }
}

// ---------------- aggregation: t = relu(dn*sum(w_e*h_s) + dn^2*h_n + b), fused BN stats --------
// ONE NODE PER LANE-GROUP, serial edge loop over packed 8B records, unroll x2.
template<int CH, bool FP16OUT>
__global__ __launch_bounds__(256) void k_agg(
    const _Float16* __restrict__ h, u16* __restrict__ thi, u16* __restrict__ tlo,
    const float* __restrict__ bias,
    const int* __restrict__ off, const int2* __restrict__ es,
    const float* __restrict__ dis, float* __restrict__ statS, float* __restrict__ statQ,
    _Float16* __restrict__ tf)
{
    constexpr int ECH = 16;            // channels per lane (32B fp16)
    constexpr int LPG = CH / ECH;      // lanes per node
    constexpr int G   = 64 / LPG;      // nodes per wave
    constexpr int NB  = NN / G;        // node batches
    __shared__ float redS[CH], redQ[CH];
    const int tid = threadIdx.x;
    for (int i = tid; i < CH; i += 256) { redS[i] = 0.f; redQ[i] = 0.f; }
    __syncthreads();

    const int lane = tid & 63;
    const int g = lane / LPG;          // node slot within wave
    const int c = (lane % LPG) * ECH;  // channel offset
    const int wid = (blockIdx.x * 256 + tid) >> 6;
    const int nw = (gridDim.x * 256) >> 6;

    float bs[ECH], bq[ECH], bv[ECH];
#pragma unroll
    for (int v = 0; v < ECH; v++) { bs[v] = 0.f; bq[v] = 0.f; bv[v] = bias[c + v]; }

    for (int b = wid; b < NB; b += nw) {
        const int n = b * G + g;
        const int p0 = off[n], p1 = off[n + 1];
        float a[ECH];
#pragma unroll
        for (int v = 0; v < ECH; v++) a[v] = 0.f;

        int p = p0;
        while (p + 2 <= p1) {          // two independent row-gathers in flight
            const int2 eA = es[p], eB = es[p + 1];
            const float wA = __int_as_float(eA.y), wB = __int_as_float(eB.y);
            const _Float16* hA = h + (size_t)eA.x * CH + c;
            const _Float16* hB = h + (size_t)eB.x * CH + c;
            h8t a0 = *(const h8t*)hA;
            h8t a1 = *(const h8t*)(hA + 8);
            h8t b0 = *(const h8t*)hB;
            h8t b1 = *(const h8t*)(hB + 8);
#pragma unroll
            for (int v = 0; v < 8; v++) {
                a[v]     += wA * (float)a0[v] + wB * (float)b0[v];
                a[v + 8] += wA * (float)a1[v] + wB * (float)b1[v];
            }
            p += 2;
        }
        if (p < p1) {                  // odd tail
            const int2 eA = es[p];
            const float wA = __int_as_float(eA.y);
            const _Float16* hA = h + (size_t)eA.x * CH + c;
            h8t a0 = *(const h8t*)hA;
            h8t a1 = *(const h8t*)(hA + 8);
#pragma unroll
            for (int v = 0; v < 8; v++) { a[v] += wA * (float)a0[v]; a[v + 8] += wA * (float)a1[v]; }
        }
        // no cross-lane merge needed: this lane owns channels c..c+15 of node n
        const float dn = dis[n];
        const float dn2 = dn * dn;
        const _Float16* hr = h + (size_t)n * CH + c;
        h8t hn0 = *(const h8t*)hr;
        h8t hn1 = *(const h8t*)(hr + 8);
        float o16[ECH];
#pragma unroll
        for (int v = 0; v < 8; v++) {
            o16[v] = fmaxf(dn * a[v] + dn2 * (float)hn0[v] + bv[v], 0.f);
            o16[v + 8] = fmaxf(dn * a[v + 8] + dn2 * (float)hn1[v] + bv[v + 8], 0.f);
        }
#pragma unroll
        for (int v = 0; v < ECH; v++) { bs[v] += o16[v]; bq[v] += o16[v] * o16[v]; }
        if constexpr (FP16OUT) {
            h8t o0, o1;
#pragma unroll
            for (int v = 0; v < 8; v++) { o0[v] = (_Float16)o16[v]; o1[v] = (_Float16)o16[v + 8]; }
            _Float16* tr = tf + (size_t)n * CH + c;
            *(h8t*)tr = o0; *(h8t*)(tr + 8) = o1;
        } else {
            u16x8 hv0, lv0, hv1, lv1;
#pragma unroll
            for (int v = 0; v < 8; v++) {
                splitbf(o16[v], ((u16*)&hv0)[v], ((u16*)&lv0)[v]);
                splitbf(o16[v + 8], ((u16*)&hv1)[v], ((u16*)&lv1)[v]);
            }
            u16* th = thi + (size_t)n * CH + c;
            u16* tl = tlo + (size_t)n * CH + c;
            *(u16x8*)th = hv0; *(u16x8*)(th + 8) = hv1;
            *(u16x8*)tl = lv0; *(u16x8*)(tl + 8) = lv1;
        }
    }
    // one-time stats merge across the G node-slots of this wave
#pragma unroll
    for (int o = LPG; o < 64; o <<= 1) {
#pragma unroll
        for (int v = 0; v < ECH; v++) { bs[v] += __shfl_xor(bs[v], o); bq[v] += __shfl_xor(bq[v], o); }
    }
    if (g == 0) {
#pragma unroll
        for (int v = 0; v < ECH; v++) { atomicAdd(&redS[c + v], bs[v]); atomicAdd(&redQ[c + v], bq[v]); }
    }
    __syncthreads();
    for (int i = tid; i < CH; i += 256) { atomicAdd(&statS[i], redS[i]); atomicAdd(&statQ[i], redQ[i]); }
}

// ---------------- pure linear aggregation: u = dn*sum(w_e*t_s) + dn^2*t_n ----------------
template<int CH>
__global__ __launch_bounds__(256) void k_agglin(
    const _Float16* __restrict__ t, u16* __restrict__ uhi, u16* __restrict__ ulo,
    const int* __restrict__ off, const int2* __restrict__ es,
    const float* __restrict__ dis)
{
    constexpr int ECH = 16;
    constexpr int LPG = CH / ECH;
    constexpr int G   = 64 / LPG;
    constexpr int NB  = NN / G;
    const int tid = threadIdx.x;
    const int lane = tid & 63;
    const int g = lane / LPG;
    const int c = (lane % LPG) * ECH;
    const int wid = (blockIdx.x * 256 + tid) >> 6;
    const int nw = (gridDim.x * 256) >> 6;

    for (int b = wid; b < NB; b += nw) {
        const int n = b * G + g;
        const int p0 = off[n], p1 = off[n + 1];
        float a[ECH];
#pragma unroll
        for (int v = 0; v < ECH; v++) a[v] = 0.f;

        int p = p0;
        while (p + 2 <= p1) {
            const int2 eA = es[p], eB = es[p + 1];
            const float wA = __int_as_float(eA.y), wB = __int_as_float(eB.y);
            const _Float16* hA = t + (size_t)eA.x * CH + c;
            const _Float16* hB = t + (size_t)eB.x * CH + c;
            h8t a0 = *(const h8t*)hA;
            h8t a1 = *(const h8t*)(hA + 8);
            h8t b0 = *(const h8t*)hB;
            h8t b1 = *(const h8t*)(hB + 8);
#pragma unroll
            for (int v = 0; v < 8; v++) {
                a[v]     += wA * (float)a0[v] + wB * (float)b0[v];
                a[v + 8] += wA * (float)a1[v] + wB * (float)b1[v];
            }
            p += 2;
        }
        if (p < p1) {
            const int2 eA = es[p];
            const float wA = __int_as_float(eA.y);
            const _Float16* hA = t + (size_t)eA.x * CH + c;
            h8t a0 = *(const h8t*)hA;
            h8t a1 = *(const h8t*)(hA + 8);
#pragma unroll
            for (int v = 0; v < 8; v++) { a[v] += wA * (float)a0[v]; a[v + 8] += wA * (float)a1[v]; }
        }
        const float dn = dis[n];
        const float dn2 = dn * dn;
        const _Float16* hr = t + (size_t)n * CH + c;
        h8t hn0 = *(const h8t*)hr;
        h8t hn1 = *(const h8t*)(hr + 8);
        u16x8 hv0, lv0, hv1, lv1;
#pragma unroll
        for (int v = 0; v < 8; v++) {
            float o0 = dn * a[v] + dn2 * (float)hn0[v];
            float o1 = dn * a[v + 8] + dn2 * (float)hn1[v];
            splitbf(o0, ((u16*)&hv0)[v], ((u16*)&lv0)[v]);
            splitbf(o1, ((u16*)&hv1)[v], ((u16*)&lv1)[v]);
        }
        u16* th = uhi + (size_t)n * CH + c;
        u16* tl = ulo + (size_t)n * CH + c;
        *(u16x8*)th = hv0; *(u16x8*)(th + 8) = hv1;
        *(u16x8*)tl = lv0; *(u16x8*)(tl + 8) = lv1;
    }
}

// ---------------- small dense layer: C[N,F] = affine(A)[N,K] @ W[K,F] (+bias) ----------------
template<int K, int F, bool BIAS, bool STATS>
__global__ __launch_bounds__(256) void k_smm(
    const u16* __restrict__ Ahi, const u16* __restrict__ Alo,
    const float* __restrict__ Wf, const float* __restrict__ bias,
    _Float16* __restrict__ C,
    const float* __restrict__ Sb, const float* __restrict__ Qb,
    const float* __restrict__ gb, const float* __restrict__ bb,
    float* __restrict__ Sg, float* __restrict__ Qg)
{
    __shared__ float Wl[K * F];
    __shared__ float scl[K], shl[K], bl[F];
    __shared__ float redS[F], redQ[F];
    const int tid = threadIdx.x;
    for (int i = tid; i < K * F; i += 256) Wl[i] = Wf[i];
    if (tid < K) {
        float s, h_; bnparams(Sb, Qb, gb, bb, tid, s, h_);
        scl[tid] = s; shl[tid] = h_;
    }
    if (tid < F) {
        bl[tid] = 0.f;
        if constexpr (BIAS) bl[tid] = bias[tid];
        if constexpr (STATS) { redS[tid] = 0.f; redQ[tid] = 0.f; }
    }
    __syncthreads();
    const int n = blockIdx.x * 256 + tid;
    float acc[F];
#pragma unroll
    for (int f = 0; f < F; f++) acc[f] = bl[f];
    const u16* ah = Ahi + (size_t)n * K;
    const u16* al = Alo + (size_t)n * K;
    for (int k = 0; k < K; k += 4) {
        ushort4 hv = *(const ushort4*)(ah + k);
        ushort4 lv = *(const ushort4*)(al + k);
        float y0 = (bf2f(hv.x) + bf2f(lv.x)) * scl[k] + shl[k];
        float y1 = (bf2f(hv.y) + bf2f(lv.y)) * scl[k + 1] + shl[k + 1];
        float y2 = (bf2f(hv.z) + bf2f(lv.z)) * scl[k + 2] + shl[k + 2];
        float y3 = (bf2f(hv.w) + bf2f(lv.w)) * scl[k + 3] + shl[k + 3];
#pragma unroll
        for (int f = 0; f < F; f += 4) {
            float4 w0 = *(const float4*)&Wl[k * F + f];
            float4 w1 = *(const float4*)&Wl[(k + 1) * F + f];
            float4 w2 = *(const float4*)&Wl[(k + 2) * F + f];
            float4 w3 = *(const float4*)&Wl[(k + 3) * F + f];
            acc[f + 0] += y0 * w0.x + y1 * w1.x + y2 * w2.x + y3 * w3.x;
            acc[f + 1] += y0 * w0.y + y1 * w1.y + y2 * w2.y + y3 * w3.y;
            acc[f + 2] += y0 * w0.z + y1 * w1.z + y2 * w2.z + y3 * w3.z;
            acc[f + 3] += y0 * w0.w + y1 * w1.w + y2 * w2.w + y3 * w3.w;
        }
    }
    _Float16* cr = C + (size_t)n * F;
#pragma unroll
    for (int f = 0; f < F; f++) cr[f] = (_Float16)acc[f];
    if constexpr (STATS) {
        float s[F], q[F];
#pragma unroll
        for (int f = 0; f < F; f++) { s[f] = acc[f]; q[f] = acc[f] * acc[f]; }
#pragma unroll
        for (int o = 1; o < 64; o <<= 1) {
#pragma unroll
            for (int f = 0; f < F; f++) { s[f] += __shfl_xor(s[f], o); q[f] += __shfl_xor(q[f], o); }
        }
        if ((tid & 63) == 0) {
#pragma unroll
            for (int f = 0; f < F; f++) { atomicAdd(&redS[f], s[f]); atomicAdd(&redQ[f], q[f]); }
        }
        __syncthreads();
        for (int i = tid; i < F; i += 256) { atomicAdd(&Sg[i], redS[i]); atomicAdd(&Qg[i], redQ[i]); }
    }
}

// ---------------- gate layer 2: g2 = relu(bn1(g1)) @ gW2 + gb2, stats inline + fused ----------------
__global__ __launch_bounds__(256) void k_gate2(const _Float16* __restrict__ g1,
                                               const float* __restrict__ S1g, const float* __restrict__ Q1g,
                                               const float* __restrict__ gg, const float* __restrict__ gbb,
                                               const float* __restrict__ w2, const float* __restrict__ b2,
                                               float* __restrict__ g2,
                                               float* __restrict__ Sg, float* __restrict__ Qg) {
    __shared__ float wl[16], scl[16], shl[16], b2l[1];
    __shared__ float redSg[1], redQg[1];
    const int tid = threadIdx.x;
    if (tid < 16) {
        wl[tid] = w2[tid];
        float s, h_; bnparams(S1g, Q1g, gg, gbb, tid, s, h_);
        scl[tid] = s; shl[tid] = h_;
    }
    if (tid == 0) { b2l[0] = b2[0]; redSg[0] = 0.f; redQg[0] = 0.f; }
    __syncthreads();
    const int n = blockIdx.x * 256 + tid;
    const _Float16* r = g1 + (size_t)n * 16;
    float acc = b2l[0];
#pragma unroll
    for (int k = 0; k < 16; k++) {
        float y = fmaxf((float)r[k] * scl[k] + shl[k], 0.f);
        acc += y * wl[k];
    }
    g2[n] = acc;
    float s = acc, q = acc * acc;
#pragma unroll
    for (int o = 1; o < 64; o <<= 1) { s += __shfl_xor(s, o); q += __shfl_xor(q, o); }
    if ((tid & 63) == 0) { atomicAdd(&redSg[0], s); atomicAdd(&redQg[0], q); }
    __syncthreads();
    if (tid == 0) { atomicAdd(&Sg[0], redSg[0]); atomicAdd(&Qg[0], redQg[0]); }
}

// ---------------- segment softmax + pooling + FC + softmax (BN params inline) ----------------
__global__ __launch_bounds__(256) void k_pool(const u16* __restrict__ t4hi, const u16* __restrict__ t4lo,
                                              const float* __restrict__ S4, const float* __restrict__ Q4,
                                              const float* __restrict__ g4, const float* __restrict__ b4,
                                              const float* __restrict__ g2,
                                              const float* __restrict__ gS2, const float* __restrict__ gQ2,
                                              const float* __restrict__ gg2, const float* __restrict__ gbb2,
                                              const float* __restrict__ fcW, const float* __restrict__ fcb,
                                              float* __restrict__ out) {
    __shared__ float fw[32 * NCLS], fbl[NCLS], sc4l[32], sh4l[32], g2p[2];
    const int tid = threadIdx.x;
    for (int i = tid; i < 32 * NCLS; i += 256) fw[i] = fcW[i];
    if (tid < NCLS) fbl[tid] = fcb[tid];
    if (tid < 32) {
        float s, h_; bnparams(S4, Q4, g4, b4, tid, s, h_);
        sc4l[tid] = s; sh4l[tid] = h_;
    }
    if (tid == 0) {
        float s, h_; bnparams(gS2, gQ2, gg2, gbb2, 0, s, h_);
        g2p[0] = s; g2p[1] = h_;
    }
    __syncthreads();
    const int b = blockIdx.x * 256 + tid;
    const float s2 = g2p[0], h2 = g2p[1];
    const int base = b * GSZ;

    float gv[GSZ];
    float m = -1e30f;
#pragma unroll
    for (int i = 0; i < GSZ; i++) {
        float v = fmaxf(g2[base + i] * s2 + h2, 0.f);
        gv[i] = v; m = fmaxf(m, v);
    }
    float ssum = 0.f;
#pragma unroll
    for (int i = 0; i < GSZ; i++) { float e = __expf(gv[i] - m); gv[i] = e; ssum += e; }
    const float inv = 1.0f / ssum;

    float pooled[32];
#pragma unroll
    for (int c = 0; c < 32; c++) pooled[c] = 0.f;
#pragma unroll
    for (int i = 0; i < GSZ; i++) {
        const float a = gv[i] * inv;
        const u16* th = t4hi + (size_t)(base + i) * 32;
        const u16* tl = t4lo + (size_t)(base + i) * 32;
#pragma unroll
        for (int c = 0; c < 32; c += 4) {
            ushort4 hv = *(const ushort4*)(th + c);
            ushort4 lv = *(const ushort4*)(tl + c);
            pooled[c + 0] += a * ((bf2f(hv.x) + bf2f(lv.x)) * sc4l[c + 0] + sh4l[c + 0]);
            pooled[c + 1] += a * ((bf2f(hv.y) + bf2f(lv.y)) * sc4l[c + 1] + sh4l[c + 1]);
            pooled[c + 2] += a * ((bf2f(hv.z) + bf2f(lv.z)) * sc4l[c + 2] + sh4l[c + 2]);
            pooled[c + 3] += a * ((bf2f(hv.w) + bf2f(lv.w)) * sc4l[c + 3] + sh4l[c + 3]);
        }
    }
    float lg[NCLS];
    float mx = -1e30f;
#pragma unroll
    for (int j = 0; j < NCLS; j++) {
        float a = fbl[j];
#pragma unroll
        for (int c = 0; c < 32; c++) a += pooled[c] * fw[c * NCLS + j];
        lg[j] = a; mx = fmaxf(mx, a);
    }
    float es = 0.f;
#pragma unroll
    for (int j = 0; j < NCLS; j++) { float e = __expf(lg[j] - mx); lg[j] = e; es += e; }
    const float iv = 1.0f / es;
#pragma unroll
    for (int j = 0; j < NCLS; j++) out[b * NCLS + j] = lg[j] * iv;
}

// ---------------- host ----------------
extern "C" void kernel_launch(void* const* d_in, const int* in_sizes, int n_in,
                              void* d_out, int out_size, void* d_ws, size_t ws_size,
                              hipStream_t stream) {
    (void)in_sizes; (void)n_in; (void)out_size; (void)ws_size;
    const float* x    = (const float*)d_in[0];
    const int*   ei   = (const int*)d_in[1];
    const float* W1   = (const float*)d_in[2];
    const float* b1   = (const float*)d_in[3];
    const float* bn1g = (const float*)d_in[4];
    const float* bn1b = (const float*)d_in[5];
    const float* W2   = (const float*)d_in[6];
    const float* b2   = (const float*)d_in[7];
    const float* bn2g = (const float*)d_in[8];
    const float* bn2b = (const float*)d_in[9];
    const float* W3   = (const float*)d_in[10];
    const float* b3   = (const float*)d_in[11];
    const float* bn3g = (const float*)d_in[12];
    const float* bn3b = (const float*)d_in[13];
    const float* W4   = (const float*)d_in[14];
    const float* b4   = (const float*)d_in[15];
    const float* bn4g = (const float*)d_in[16];
    const float* bn4b = (const float*)d_in[17];
    const float* gW1  = (const float*)d_in[18];
    const float* gb1  = (const float*)d_in[19];
    const float* gbn1g = (const float*)d_in[20];
    const float* gbn1b = (const float*)d_in[21];
    const float* gW2  = (const float*)d_in[22];
    const float* gb2  = (const float*)d_in[23];
    const float* gbn2g = (const float*)d_in[24];
    const float* gbn2b = (const float*)d_in[25];
    const float* fcW  = (const float*)d_in[26];
    const float* fcb  = (const float*)d_in[27];
    float* out = (float*)d_out;

    char* base = (char*)d_ws;
    size_t off_ = 0;
    auto carve = [&](size_t bytes) -> char* {
        char* p = base + off_;
        off_ = (off_ + bytes + 255) & ~(size_t)255;
        return p;
    };
    int*   counts = (int*)carve((size_t)NN * 4);
    float* stats  = (float*)carve(994 * 4);
    float* wsa    = (float*)carve((size_t)NN * 4);
    float* c2_2   = (float*)carve(256 * 4);
    float* c2_3   = (float*)carve(64 * 4);
    const size_t zero_bytes = off_;
    int*   offs   = (int*)carve((size_t)(NN + 1) * 4);
    int*   cursor = (int*)carve((size_t)NN * 4);
    int2*  es     = (int2*)carve((size_t)NE * 8);
    float* dis    = (float*)carve((size_t)NN * 4);
    int*   bsum   = (int*)carve(NSCAN * 4);
    u16*   Wt1h   = (u16*)carve(512 * 128 * 2);
    u16*   Wt1l   = (u16*)carve(512 * 128 * 2);
    u16*   Wt2h   = (u16*)carve(128 * 256 * 2);
    u16*   Wt2l   = (u16*)carve(128 * 256 * 2);
    u16*   Wt3h   = (u16*)carve(256 * 64 * 2);
    u16*   Wt3l   = (u16*)carve(256 * 64 * 2);
    float* g2raw  = (float*)carve((size_t)NN * 4);
    _Float16* P   = (_Float16*)carve((size_t)NN * 256 * 2);   // h buffer (fp16, up to 256 ch)
    u16*   Qhi    = (u16*)carve((size_t)NN * 128 * 2);        // t/u planes (<=128 ch)
    u16*   Qlo    = (u16*)carve((size_t)NN * 128 * 2);
    u16*   Rhi    = (u16*)carve((size_t)NN * 256 * 2);        // t2 planes (256 ch)
    u16*   Rlo    = (u16*)carve((size_t)NN * 256 * 2);
    // t1 fp16 single plane lives in the upper half of P (h1 only uses [N,128])
    _Float16* T1f = P + (size_t)NN * 128;

    float* S1 = stats;      float* Q1s = S1 + 128;
    float* S2 = Q1s + 128;  float* Q2s = S2 + 256;
    float* S3 = Q2s + 256;  float* Q3s = S3 + 64;
    float* S4 = Q3s + 64;   float* Q4s = S4 + 32;
    float* gS1 = Q4s + 32;  float* gQ1 = gS1 + 16;
    float* gS2 = gQ1 + 16;  float* gQ2 = gS2 + 1;

    hipMemsetAsync(d_ws, 0, zero_bytes, stream);

    k_hist<<<NE / 256, 256, 0, stream>>>(ei, counts);
    k_scan1<<<NSCAN, 256, 0, stream>>>(counts, bsum);
    k_scan2<<<1, 128, 0, stream>>>(bsum, offs);
    k_scan3<<<NSCAN, 256, 0, stream>>>(counts, bsum, offs, dis, cursor);
    k_scatter<<<NE / 256, 256, 0, stream>>>(ei, cursor, es, dis, wsa);
    k_tsplit<<<(512 * 128 + 255) / 256, 256, 0, stream>>>(W1, Wt1h, Wt1l, 512, 128);

    // layer 1: h1 = x @ W1 -> P (N x 128 fp16); t1 = relu(agg(h1)+b1) -> T1f fp16 + BN1 stats
    k_gemm<128, 128, 2, true, false, false><<<dim3(1, NN / 128), 256, 0, stream>>>(
        x, nullptr, nullptr, Wt1h, Wt1l, P, 512, 128, nullptr,
        nullptr, nullptr, nullptr, nullptr, nullptr, nullptr, nullptr);
    k_agg<128, true><<<1792, 256, 0, stream>>>(P, nullptr, nullptr, b1, offs, es, dis, S1, Q1s, T1f);

    // layer 2, agg-commute: u = agg(t1) on 128 ch -> Q planes; then
    // t2 = relu(u@(sc1*W2) + wsum*(sh1@W2) + b2) in the GEMM epilogue -> R planes + BN2 stats
    k_agglin<128><<<1792, 256, 0, stream>>>(T1f, Qhi, Qlo, offs, es, dis);
    k_wsplit<<<(128 * 256 + 255) / 256, 256, 0, stream>>>(W2, S1, Q1s, bn1g, bn1b,
                                                          Wt2h, Wt2l, c2_2, 128, 256);
    k_gemm<128, 128, 2, false, false, true><<<dim3(2, NN / 128), 256, 0, stream>>>(
        nullptr, Qhi, Qlo, Wt2h, Wt2l, nullptr, 128, 256, c2_2,
        b2, wsa, dis, Rhi, Rlo, S2, Q2s);

    // layer 3 (BN folded into W3): h3 = t2 @ W3' + c2 -> P (N x 64); t3 -> Q planes
    k_wsplit<<<(256 * 64 + 255) / 256, 256, 0, stream>>>(W3, S2, Q2s, bn2g, bn2b,
                                                         Wt3h, Wt3l, c2_3, 256, 64);
    k_gemm<256, 64, 1, false, true, false><<<dim3(1, NN / 256), 256, 0, stream>>>(
        nullptr, Rhi, Rlo, Wt3h, Wt3l, P, 256, 64, c2_3,
        nullptr, nullptr, nullptr, nullptr, nullptr, nullptr, nullptr);
    k_agg<64, false><<<1792, 256, 0, stream>>>(P, Qhi, Qlo, b3, offs, es, dis, S3, Q3s, nullptr);

    // layer 4: h4 = bn3(t3) @ W4 -> P (N x 32 fp16); t4 -> Q planes (32 ch)
    k_smm<64, 32, false, false><<<NN / 256, 256, 0, stream>>>(Qhi, Qlo, W4, nullptr, P,
                                                              S3, Q3s, bn3g, bn3b, nullptr, nullptr);
    k_agg<32, false><<<896, 256, 0, stream>>>(P, Qhi, Qlo, b4, offs, es, dis, S4, Q4s, nullptr);

    // gate 1: g1 = bn4(t4) @ gW1 + gb1 -> P (N x 16 fp16), stats fused
    k_smm<32, 16, true, true><<<NN / 256, 256, 0, stream>>>(Qhi, Qlo, gW1, gb1, P,
                                                            S4, Q4s, bn4g, bn4b, gS1, gQ1);

    // gate 2: g2 = relu(gbn1(g1)) @ gW2 + gb2 -> g2raw (N, fp32), stats fused
    k_gate2<<<NN / 256, 256, 0, stream>>>(P, gS1, gQ1, gbn1g, gbn1b, gW2, gb2, g2raw, gS2, gQ2);

    // pooling + FC + softmax (BN4 + gate-BN2 params computed inline)
    k_pool<<<NBATCH / 256, 256, 0, stream>>>(Qhi, Qlo, S4, Q4s, bn4g, bn4b,
                                             g2raw, gS2, gQ2, gbn2g, gbn2b, fcW, fcb, out);
}